// Round 1
// baseline (850.881 us; speedup 1.0000x reference)
//
#include <hip/hip_runtime.h>
#include <cstddef>
#include <cstdint>

#define NNODES 500000
#define DIM    128
#define NSEG   8192
#define TSTEPS 6

// ---------------------------------------------------------------------------
// Segment bounds: batch is sorted; seg[b] = lower_bound(batch, b), seg[B] = N.
// ---------------------------------------------------------------------------
__global__ void seg_bounds_k(const int* __restrict__ batch, int* __restrict__ seg, int n) {
    int b = blockIdx.x * blockDim.x + threadIdx.x;
    if (b > NSEG) return;
    int lo = 0, hi = n;
    while (lo < hi) {
        int mid = (lo + hi) >> 1;
        if (batch[mid] < b) lo = mid + 1; else hi = mid;
    }
    seg[b] = lo;
}

// ---------------------------------------------------------------------------
// gates = q_star @ W_ih^T + h @ W_hh^T   (biases added in lstm_cell)
// M=8192 rows, N=512 cols, K=384 (256 from q_star, 128 from h).
// fp32 vector GEMM: 64x64 tile, 4x4 microtile, BK=32, 256 threads.
// ---------------------------------------------------------------------------
__global__ __launch_bounds__(256) void gemm_gates_k(
    const float* __restrict__ qstar, const float* __restrict__ hbuf,
    const float* __restrict__ Wih,   const float* __restrict__ Whh,
    float* __restrict__ gates)
{
    __shared__ float As[32][68];   // [k][m], pad to 68 (16B-aligned rows)
    __shared__ float Bs[32][68];   // [k][n]
    const int tid = threadIdx.x;
    const int m0 = blockIdx.y * 64;
    const int n0 = blockIdx.x * 64;
    const int tx = tid & 15, ty = tid >> 4;
    const int lrow = tid >> 2;          // 0..63
    const int lkq  = (tid & 3) << 3;    // 0,8,16,24

    float acc[4][4] = {};

    for (int kt = 0; kt < 384; kt += 32) {
        const float *asrc, *bsrc;
        if (kt < 256) {
            asrc = qstar + (size_t)(m0 + lrow) * 256 + kt + lkq;
            bsrc = Wih   + (size_t)(n0 + lrow) * 256 + kt + lkq;
        } else {
            asrc = hbuf  + (size_t)(m0 + lrow) * 128 + (kt - 256) + lkq;
            bsrc = Whh   + (size_t)(n0 + lrow) * 128 + (kt - 256) + lkq;
        }
        float4 a0 = *(const float4*)(asrc);
        float4 a1 = *(const float4*)(asrc + 4);
        float4 b0 = *(const float4*)(bsrc);
        float4 b1 = *(const float4*)(bsrc + 4);
        As[lkq+0][lrow]=a0.x; As[lkq+1][lrow]=a0.y; As[lkq+2][lrow]=a0.z; As[lkq+3][lrow]=a0.w;
        As[lkq+4][lrow]=a1.x; As[lkq+5][lrow]=a1.y; As[lkq+6][lrow]=a1.z; As[lkq+7][lrow]=a1.w;
        Bs[lkq+0][lrow]=b0.x; Bs[lkq+1][lrow]=b0.y; Bs[lkq+2][lrow]=b0.z; Bs[lkq+3][lrow]=b0.w;
        Bs[lkq+4][lrow]=b1.x; Bs[lkq+5][lrow]=b1.y; Bs[lkq+6][lrow]=b1.z; Bs[lkq+7][lrow]=b1.w;
        __syncthreads();

        #pragma unroll
        for (int kk = 0; kk < 32; ++kk) {
            float4 av = *(const float4*)&As[kk][ty << 2];
            float4 bv = *(const float4*)&Bs[kk][tx << 2];
            float am[4] = {av.x, av.y, av.z, av.w};
            float bm[4] = {bv.x, bv.y, bv.z, bv.w};
            #pragma unroll
            for (int i = 0; i < 4; ++i)
                #pragma unroll
                for (int j = 0; j < 4; ++j)
                    acc[i][j] = fmaf(am[i], bm[j], acc[i][j]);
        }
        __syncthreads();
    }

    #pragma unroll
    for (int i = 0; i < 4; ++i) {
        int row = m0 + (ty << 2) + i;
        #pragma unroll
        for (int j = 0; j < 4; ++j)
            gates[(size_t)row * 512 + n0 + (tx << 2) + j] = acc[i][j];
    }
}

// ---------------------------------------------------------------------------
// LSTM cell elementwise: i,f,g,o -> c,h ; writes q = h into d_out[:,0:128].
// ---------------------------------------------------------------------------
__global__ __launch_bounds__(256) void lstm_cell_k(
    const float* __restrict__ gates, const float* __restrict__ bih,
    const float* __restrict__ bhh,   float* __restrict__ cbuf,
    float* __restrict__ hbuf,        float* __restrict__ qstar)
{
    int idx = blockIdx.x * 256 + threadIdx.x;   // b*128 + d
    int b = idx >> 7, d = idx & 127;
    const float* g = gates + (size_t)b * 512;
    float gi = g[d]       + bih[d]       + bhh[d];
    float gf = g[128 + d] + bih[128 + d] + bhh[128 + d];
    float gg = g[256 + d] + bih[256 + d] + bhh[256 + d];
    float go = g[384 + d] + bih[384 + d] + bhh[384 + d];
    float iv = 1.f / (1.f + expf(-gi));
    float fv = 1.f / (1.f + expf(-gf));
    float gv = tanhf(gg);
    float ov = 1.f / (1.f + expf(-go));
    float c  = fv * cbuf[idx] + iv * gv;
    float h  = ov * tanhf(c);
    cbuf[idx] = c;
    hbuf[idx] = h;
    qstar[(size_t)b * 256 + d] = h;
}

// ---------------------------------------------------------------------------
// e[n] = dot(x[n], h[batch[n]]) — 16 lanes per node, float4 loads.
// ---------------------------------------------------------------------------
__global__ __launch_bounds__(256) void compute_e_k(
    const float* __restrict__ x, const int* __restrict__ batch,
    const float* __restrict__ hbuf, float* __restrict__ e)
{
    int grp  = threadIdx.x >> 4;
    int lane = threadIdx.x & 15;
    int n = blockIdx.x * 16 + grp;
    if (n >= NNODES) return;
    int b = batch[n];
    const float4* xp = (const float4*)(x    + (size_t)n * DIM);
    const float4* hp = (const float4*)(hbuf + (size_t)b * DIM);
    float4 xa = xp[lane],      ha = hp[lane];
    float4 xb = xp[16 + lane], hb = hp[16 + lane];
    float s = xa.x*ha.x + xa.y*ha.y + xa.z*ha.z + xa.w*ha.w
            + xb.x*hb.x + xb.y*hb.y + xb.z*hb.z + xb.w*hb.w;
    s += __shfl_xor(s, 1);
    s += __shfl_xor(s, 2);
    s += __shfl_xor(s, 4);
    s += __shfl_xor(s, 8);
    if (lane == 0) e[n] = s;
}

// ---------------------------------------------------------------------------
// Per-segment: softmax stats over e, then r = sum a[n]*x[n].
// One block (128 threads = D) per segment; writes d_out[:,128:256].
// ---------------------------------------------------------------------------
__global__ __launch_bounds__(128) void seg_attn_k(
    const float* __restrict__ x, const float* __restrict__ e,
    const int* __restrict__ seg, float* __restrict__ qstar)
{
    int b = blockIdx.x;
    int ns = seg[b], ne = seg[b + 1];
    int tid = threadIdx.x;
    __shared__ float red[2];
    __shared__ float coef[128];

    // segment max
    float m = -INFINITY;
    for (int j = ns + tid; j < ne; j += 128) m = fmaxf(m, e[j]);
    #pragma unroll
    for (int o = 1; o < 64; o <<= 1) m = fmaxf(m, __shfl_xor(m, o));
    if ((tid & 63) == 0) red[tid >> 6] = m;
    __syncthreads();
    m = fmaxf(red[0], red[1]);
    __syncthreads();

    // denom
    float s = 0.f;
    for (int j = ns + tid; j < ne; j += 128) s += expf(e[j] - m);
    #pragma unroll
    for (int o = 1; o < 64; o <<= 1) s += __shfl_xor(s, o);
    if ((tid & 63) == 0) red[tid >> 6] = s;
    __syncthreads();
    float rden = 1.f / (red[0] + red[1] + 1e-16f);

    // weighted sum: thread tid owns dimension d = tid
    float r = 0.f;
    for (int c0 = ns; c0 < ne; c0 += 128) {
        __syncthreads();
        int j = c0 + tid;
        coef[tid] = (j < ne) ? expf(e[j] - m) * rden : 0.f;
        __syncthreads();
        int cnt = min(128, ne - c0);
        for (int jj = 0; jj < cnt; ++jj)
            r = fmaf(coef[jj], x[(size_t)(c0 + jj) * DIM + tid], r);
    }
    qstar[(size_t)b * 256 + DIM + tid] = r;
}

// ---------------------------------------------------------------------------
extern "C" void kernel_launch(void* const* d_in, const int* in_sizes, int n_in,
                              void* d_out, int out_size, void* d_ws, size_t ws_size,
                              hipStream_t stream) {
    const float* x     = (const float*)d_in[0];
    const int*   batch = (const int*)d_in[1];
    const float* Wih   = (const float*)d_in[2];
    const float* Whh   = (const float*)d_in[3];
    const float* bih   = (const float*)d_in[4];
    const float* bhh   = (const float*)d_in[5];
    float* out = (float*)d_out;

    // workspace layout (floats)
    float* hbuf  = (float*)d_ws;                      // 8192*128   = 4 MB
    float* cbuf  = hbuf  + (size_t)NSEG * DIM;        // 4 MB
    float* gates = cbuf  + (size_t)NSEG * DIM;        // 8192*512   = 16 MB
    float* ebuf  = gates + (size_t)NSEG * 512;        // 500000     = 2 MB
    int*   seg   = (int*)(ebuf + NNODES);             // 8193 ints

    hipMemsetAsync(hbuf, 0, (size_t)NSEG * DIM * sizeof(float), stream);
    hipMemsetAsync(cbuf, 0, (size_t)NSEG * DIM * sizeof(float), stream);
    hipMemsetAsync(out,  0, (size_t)NSEG * 2 * DIM * sizeof(float), stream);

    seg_bounds_k<<<(NSEG + 256) / 256, 256, 0, stream>>>(batch, seg, NNODES);

    dim3 ggrid(8, 128);   // 512/64 cols, 8192/64 rows
    for (int t = 0; t < TSTEPS; ++t) {
        gemm_gates_k<<<ggrid, 256, 0, stream>>>(out, hbuf, Wih, Whh, gates);
        lstm_cell_k<<<(NSEG * DIM) / 256, 256, 0, stream>>>(gates, bih, bhh, cbuf, hbuf, out);
        compute_e_k<<<(NNODES + 15) / 16, 256, 0, stream>>>(x, batch, hbuf, ebuf);
        seg_attn_k<<<NSEG, 128, 0, stream>>>(x, ebuf, seg, out);
    }
}

// Round 3
// 815.037 us; speedup vs baseline: 1.0440x; 1.0440x over previous
//
#include <hip/hip_runtime.h>
#include <cstddef>
#include <cstdint>

#define NNODES 500000
#define DIM    128
#define NSEG   8192
#define TSTEPS 6
#define CAP    384     // LDS chunk capacity (max seg ~95 for this input; online-softmax handles overflow)

// ---------------------------------------------------------------------------
// Segment bounds: batch is sorted; seg[b] = lower_bound(batch, b), seg[B] = N.
// ---------------------------------------------------------------------------
__global__ void seg_bounds_k(const int* __restrict__ batch, int* __restrict__ seg, int n) {
    int b = blockIdx.x * blockDim.x + threadIdx.x;
    if (b > NSEG) return;
    int lo = 0, hi = n;
    while (lo < hi) {
        int mid = (lo + hi) >> 1;
        if (batch[mid] < b) lo = mid + 1; else hi = mid;
    }
    seg[b] = lo;
}

// ---------------------------------------------------------------------------
// gates = q_star @ W_ih^T + h @ W_hh^T   (biases added in lstm_cell)
// M=8192, N=512, K=384. fp32 vector GEMM: 64x64 tile, 4x4 microtile, BK=32.
// ---------------------------------------------------------------------------
__global__ __launch_bounds__(256) void gemm_gates_k(
    const float* __restrict__ qstar, const float* __restrict__ hbuf,
    const float* __restrict__ Wih,   const float* __restrict__ Whh,
    float* __restrict__ gates)
{
    __shared__ float As[32][68];
    __shared__ float Bs[32][68];
    const int tid = threadIdx.x;
    const int m0 = blockIdx.y * 64;
    const int n0 = blockIdx.x * 64;
    const int tx = tid & 15, ty = tid >> 4;
    const int lrow = tid >> 2;
    const int lkq  = (tid & 3) << 3;

    float acc[4][4] = {};

    for (int kt = 0; kt < 384; kt += 32) {
        const float *asrc, *bsrc;
        if (kt < 256) {
            asrc = qstar + (size_t)(m0 + lrow) * 256 + kt + lkq;
            bsrc = Wih   + (size_t)(n0 + lrow) * 256 + kt + lkq;
        } else {
            asrc = hbuf  + (size_t)(m0 + lrow) * 128 + (kt - 256) + lkq;
            bsrc = Whh   + (size_t)(n0 + lrow) * 128 + (kt - 256) + lkq;
        }
        float4 a0 = *(const float4*)(asrc);
        float4 a1 = *(const float4*)(asrc + 4);
        float4 b0 = *(const float4*)(bsrc);
        float4 b1 = *(const float4*)(bsrc + 4);
        As[lkq+0][lrow]=a0.x; As[lkq+1][lrow]=a0.y; As[lkq+2][lrow]=a0.z; As[lkq+3][lrow]=a0.w;
        As[lkq+4][lrow]=a1.x; As[lkq+5][lrow]=a1.y; As[lkq+6][lrow]=a1.z; As[lkq+7][lrow]=a1.w;
        Bs[lkq+0][lrow]=b0.x; Bs[lkq+1][lrow]=b0.y; Bs[lkq+2][lrow]=b0.z; Bs[lkq+3][lrow]=b0.w;
        Bs[lkq+4][lrow]=b1.x; Bs[lkq+5][lrow]=b1.y; Bs[lkq+6][lrow]=b1.z; Bs[lkq+7][lrow]=b1.w;
        __syncthreads();

        #pragma unroll
        for (int kk = 0; kk < 32; ++kk) {
            float4 av = *(const float4*)&As[kk][ty << 2];
            float4 bv = *(const float4*)&Bs[kk][tx << 2];
            float am[4] = {av.x, av.y, av.z, av.w};
            float bm[4] = {bv.x, bv.y, bv.z, bv.w};
            #pragma unroll
            for (int i = 0; i < 4; ++i)
                #pragma unroll
                for (int j = 0; j < 4; ++j)
                    acc[i][j] = fmaf(am[i], bm[j], acc[i][j]);
        }
        __syncthreads();
    }

    #pragma unroll
    for (int i = 0; i < 4; ++i) {
        int row = m0 + (ty << 2) + i;
        #pragma unroll
        for (int j = 0; j < 4; ++j)
            gates[(size_t)row * 512 + n0 + (tx << 2) + j] = acc[i][j];
    }
}

// ---------------------------------------------------------------------------
// LSTM cell elementwise: i,f,g,o -> c,h ; writes q = h into d_out[:,0:128].
// ---------------------------------------------------------------------------
__global__ __launch_bounds__(256) void lstm_cell_k(
    const float* __restrict__ gates, const float* __restrict__ bih,
    const float* __restrict__ bhh,   float* __restrict__ cbuf,
    float* __restrict__ hbuf,        float* __restrict__ qstar)
{
    int idx = blockIdx.x * 256 + threadIdx.x;   // b*128 + d
    int b = idx >> 7, d = idx & 127;
    const float* g = gates + (size_t)b * 512;
    float gi = g[d]       + bih[d]       + bhh[d];
    float gf = g[128 + d] + bih[128 + d] + bhh[128 + d];
    float gg = g[256 + d] + bih[256 + d] + bhh[256 + d];
    float go = g[384 + d] + bih[384 + d] + bhh[384 + d];
    float iv = 1.f / (1.f + expf(-gi));
    float fv = 1.f / (1.f + expf(-gf));
    float gv = tanhf(gg);
    float ov = 1.f / (1.f + expf(-go));
    float c  = fv * cbuf[idx] + iv * gv;
    float h  = ov * tanhf(c);
    cbuf[idx] = c;
    hbuf[idx] = h;
    qstar[(size_t)b * 256 + d] = h;
}

// ---------------------------------------------------------------------------
// Fused attention: per segment b, e[n]=dot(x[n],h[b]) -> online softmax ->
// r = sum a[n]*x[n]. One 128-thread block per segment. x read once from
// HBM/L3 (pass 1); pass 3 re-reads same rows from L1/L2.
// ---------------------------------------------------------------------------
__global__ __launch_bounds__(128) void seg_attn_fused_k(
    const float* __restrict__ x, const int* __restrict__ seg,
    const float* __restrict__ hbuf, float* __restrict__ qstar)
{
    const int b   = blockIdx.x;
    const int ns  = seg[b], ne = seg[b + 1];
    const int tid = threadIdx.x;
    const int lane = tid & 15, grp = tid >> 4;   // 8 groups of 16 lanes

    __shared__ float es[CAP];
    __shared__ float red[2];

    // h[b] fragment: lane holds elements [lane*4, lane*4+4) and [64+lane*4, ...)
    const float4* hp = (const float4*)(hbuf + (size_t)b * DIM);
    const float4 h0 = hp[lane];
    const float4 h1 = hp[lane + 16];

    float m = -INFINITY;   // running max (uniform across threads)
    float den = 0.f;       // running denom
    float r = 0.f;         // running weighted sum for dim tid (pre-normalization)

    for (int c0 = ns; c0 < ne; c0 += CAP) {
        const int cc = min(CAP, ne - c0);

        __syncthreads();   // protect es from previous chunk's readers
        // pass 1: e for chunk, 8 nodes in flight (one per 16-lane group)
        for (int j = c0 + grp; j < c0 + cc; j += 8) {
            const float4* xp = (const float4*)(x + (size_t)j * DIM);
            float4 xa = xp[lane], xb = xp[lane + 16];
            float s = xa.x*h0.x + xa.y*h0.y + xa.z*h0.z + xa.w*h0.w
                    + xb.x*h1.x + xb.y*h1.y + xb.z*h1.z + xb.w*h1.w;
            s += __shfl_xor(s, 1);
            s += __shfl_xor(s, 2);
            s += __shfl_xor(s, 4);
            s += __shfl_xor(s, 8);
            if (lane == 0) es[j - c0] = s;
        }
        __syncthreads();

        // chunk max (block reduce over 128 threads)
        float cm = -INFINITY;
        for (int i = tid; i < cc; i += 128) cm = fmaxf(cm, es[i]);
        #pragma unroll
        for (int o = 1; o < 64; o <<= 1) cm = fmaxf(cm, __shfl_xor(cm, o));
        if ((tid & 63) == 0) red[tid >> 6] = cm;
        __syncthreads();
        cm = fmaxf(red[0], red[1]);
        __syncthreads();

        const float mn = fmaxf(m, cm);
        const float scale = expf(m - mn);   // m=-inf first chunk -> 0

        // exp in place + chunk denom
        float cd = 0.f;
        for (int i = tid; i < cc; i += 128) {
            float v = expf(es[i] - mn);
            es[i] = v;
            cd += v;
        }
        #pragma unroll
        for (int o = 1; o < 64; o <<= 1) cd += __shfl_xor(cd, o);
        if ((tid & 63) == 0) red[tid >> 6] = cd;
        __syncthreads();                     // also publishes es[] exp values
        cd = red[0] + red[1];
        __syncthreads();

        den = den * scale + cd;
        r  *= scale;

        // pass 3: weighted sum, thread tid owns dim tid; rows hot in L1/L2
        const float* xb2 = x + (size_t)c0 * DIM + tid;
        int jj = 0;
        for (; jj + 3 < cc; jj += 4) {
            float w0 = es[jj], w1 = es[jj+1], w2 = es[jj+2], w3 = es[jj+3];
            r = fmaf(w0, xb2[(size_t)(jj+0) * DIM], r);
            r = fmaf(w1, xb2[(size_t)(jj+1) * DIM], r);
            r = fmaf(w2, xb2[(size_t)(jj+2) * DIM], r);
            r = fmaf(w3, xb2[(size_t)(jj+3) * DIM], r);
        }
        for (; jj < cc; ++jj) r = fmaf(es[jj], xb2[(size_t)jj * DIM], r);

        m = mn;
    }

    qstar[(size_t)b * 256 + DIM + tid] = r / (den + 1e-16f);
}

// ---------------------------------------------------------------------------
extern "C" void kernel_launch(void* const* d_in, const int* in_sizes, int n_in,
                              void* d_out, int out_size, void* d_ws, size_t ws_size,
                              hipStream_t stream) {
    const float* x     = (const float*)d_in[0];
    const int*   batch = (const int*)d_in[1];
    const float* Wih   = (const float*)d_in[2];
    const float* Whh   = (const float*)d_in[3];
    const float* bih   = (const float*)d_in[4];
    const float* bhh   = (const float*)d_in[5];
    float* out = (float*)d_out;

    // workspace layout (floats)
    float* hbuf  = (float*)d_ws;                      // 8192*128
    float* cbuf  = hbuf  + (size_t)NSEG * DIM;
    float* gates = cbuf  + (size_t)NSEG * DIM;        // 8192*512
    int*   seg   = (int*)(gates + (size_t)NSEG * 512);

    hipMemsetAsync(hbuf, 0, (size_t)NSEG * DIM * sizeof(float), stream);
    hipMemsetAsync(cbuf, 0, (size_t)NSEG * DIM * sizeof(float), stream);
    hipMemsetAsync(out,  0, (size_t)NSEG * 2 * DIM * sizeof(float), stream);

    seg_bounds_k<<<(NSEG + 256) / 256, 256, 0, stream>>>(batch, seg, NNODES);

    dim3 ggrid(8, 128);
    for (int t = 0; t < TSTEPS; ++t) {
        gemm_gates_k<<<ggrid, 256, 0, stream>>>(out, hbuf, Wih, Whh, gates);
        lstm_cell_k<<<(NSEG * DIM) / 256, 256, 0, stream>>>(gates, bih, bhh, cbuf, hbuf, out);
        seg_attn_fused_k<<<NSEG, 128, 0, stream>>>(x, seg, hbuf, out);
    }
}

// Round 4
// 715.779 us; speedup vs baseline: 1.1887x; 1.1387x over previous
//
#include <hip/hip_runtime.h>
#include <hip/hip_bf16.h>
#include <cstddef>
#include <cstdint>

#define NNODES 500000
#define DIM    128
#define NSEG   8192
#define TSTEPS 6
#define CAP    384

typedef __attribute__((ext_vector_type(8))) short bf16x8;
typedef __attribute__((ext_vector_type(4))) float f32x4;

// ---------------------------------------------------------------------------
// Segment bounds: batch is sorted; seg[b] = lower_bound(batch, b), seg[B] = N.
// ---------------------------------------------------------------------------
__global__ void seg_bounds_k(const int* __restrict__ batch, int* __restrict__ seg, int n) {
    int b = blockIdx.x * blockDim.x + threadIdx.x;
    if (b > NSEG) return;
    int lo = 0, hi = n;
    while (lo < hi) {
        int mid = (lo + hi) >> 1;
        if (batch[mid] < b) lo = mid + 1; else hi = mid;
    }
    seg[b] = lo;
}

// ---------------------------------------------------------------------------
// One-time: wbuf[n][k] bf16, k<256 from Wih[n][k], else Whh[n][k-256].
// ---------------------------------------------------------------------------
__global__ __launch_bounds__(256) void wconv_k(
    const float* __restrict__ Wih, const float* __restrict__ Whh,
    __hip_bfloat16* __restrict__ wbuf)
{
    int idx = blockIdx.x * 256 + threadIdx.x;    // 512*384 exact
    int n = idx / 384, k = idx - n * 384;
    float v = (k < 256) ? Wih[n * 256 + k] : Whh[n * 128 + (k - 256)];
    wbuf[idx] = __float2bfloat16(v);
}

// ---------------------------------------------------------------------------
// gates = Abf @ Wbf^T  (fp32 accumulate). A=[8192][384] bf16 = [q|r|h],
// W=[512][384] bf16. MFMA 16x16x32, BM=128 BN=64 BK=64, 4 waves (2x2),
// XOR-swizzled LDS, issue-early staging.
// ---------------------------------------------------------------------------
__global__ __launch_bounds__(256) void gemm_mfma_k(
    const __hip_bfloat16* __restrict__ abuf,
    const __hip_bfloat16* __restrict__ wbuf,
    float* __restrict__ gates)
{
    __shared__ char As[128 * 128];   // 128 rows x 128 B (64 bf16 of K-window)
    __shared__ char Bs[64 * 128];
    const int tid  = threadIdx.x;
    const int lane = tid & 63, wave = tid >> 6;
    const int wrow = (wave >> 1) * 64;   // 0 / 64
    const int wcol = (wave & 1) * 32;    // 0 / 32
    const int m0 = blockIdx.y * 128;
    const int n0 = blockIdx.x * 64;

    // staging: A row per 2 threads (64 B each), B row per 4 threads (32 B each)
    const int ar  = tid >> 1;
    const int acb = (tid & 1) * 64;
    const int br  = tid >> 2;
    const int bcb = (tid & 3) * 32;

    const char* aP = (const char*)(abuf + (size_t)(m0 + ar) * 384) + acb;
    const char* bP = (const char*)(wbuf + (size_t)(n0 + br) * 384) + bcb;

    f32x4 acc[4][2] = {};

    int4 ra[4]; int4 rb2[2];
    #pragma unroll
    for (int c = 0; c < 4; ++c) ra[c]  = *(const int4*)(aP + c * 16);
    #pragma unroll
    for (int c = 0; c < 2; ++c) rb2[c] = *(const int4*)(bP + c * 16);

    char* asw = As + ar * 128;
    char* bsw = Bs + br * 128;
    const int amask = (ar & 7) << 4;
    const int bmask = (br & 7) << 4;

    for (int s = 0; s < 6; ++s) {
        __syncthreads();   // prior frag reads done
        #pragma unroll
        for (int c = 0; c < 4; ++c)
            *(int4*)(asw + ((acb + c * 16) ^ amask)) = ra[c];
        #pragma unroll
        for (int c = 0; c < 2; ++c)
            *(int4*)(bsw + ((bcb + c * 16) ^ bmask)) = rb2[c];
        __syncthreads();

        if (s < 5) {  // issue next-stage loads early; land under MFMA phase
            const char* aN = aP + (size_t)(s + 1) * 128;
            const char* bN = bP + (size_t)(s + 1) * 128;
            #pragma unroll
            for (int c = 0; c < 4; ++c) ra[c]  = *(const int4*)(aN + c * 16);
            #pragma unroll
            for (int c = 0; c < 2; ++c) rb2[c] = *(const int4*)(bN + c * 16);
        }

        #pragma unroll
        for (int ks = 0; ks < 2; ++ks) {
            const int kb = ks * 64 + ((lane >> 4) << 4);   // byte offset of lane's k-slice
            bf16x8 af[4], bfr[2];
            #pragma unroll
            for (int rbk = 0; rbk < 4; ++rbk) {
                int r = wrow + rbk * 16 + (lane & 15);
                af[rbk] = *(const bf16x8*)(As + r * 128 + (kb ^ ((r & 7) << 4)));
            }
            #pragma unroll
            for (int cb = 0; cb < 2; ++cb) {
                int n = wcol + cb * 16 + (lane & 15);
                bfr[cb] = *(const bf16x8*)(Bs + n * 128 + (kb ^ ((n & 7) << 4)));
            }
            #pragma unroll
            for (int rbk = 0; rbk < 4; ++rbk)
                #pragma unroll
                for (int cb = 0; cb < 2; ++cb)
                    acc[rbk][cb] = __builtin_amdgcn_mfma_f32_16x16x32_bf16(
                        af[rbk], bfr[cb], acc[rbk][cb], 0, 0, 0);
        }
    }

    // epilogue: C/D map col=lane&15, row=(lane>>4)*4+reg  [m89/m91-verified]
    const int rowb = (lane >> 4) << 2;
    const int coll = lane & 15;
    #pragma unroll
    for (int rbk = 0; rbk < 4; ++rbk)
        #pragma unroll
        for (int cb = 0; cb < 2; ++cb) {
            int row = m0 + wrow + rbk * 16 + rowb;
            int col = n0 + wcol + cb * 16 + coll;
            float* gp = gates + (size_t)row * 512 + col;
            #pragma unroll
            for (int reg = 0; reg < 4; ++reg)
                gp[(size_t)reg * 512] = acc[rbk][cb][reg];
        }
}

// ---------------------------------------------------------------------------
// LSTM cell elementwise; writes q=h to d_out[:,0:128], h to abuf cols [0,128)
// and [256,384) (bf16), plus fp32 hbuf/cbuf.
// ---------------------------------------------------------------------------
__global__ __launch_bounds__(256) void lstm_cell_k(
    const float* __restrict__ gates, const float* __restrict__ bih,
    const float* __restrict__ bhh,   float* __restrict__ cbuf,
    float* __restrict__ hbuf,        float* __restrict__ qstar,
    __hip_bfloat16* __restrict__ abuf)
{
    int idx = blockIdx.x * 256 + threadIdx.x;   // b*128 + d
    int b = idx >> 7, d = idx & 127;
    const float* g = gates + (size_t)b * 512;
    float gi = g[d]       + bih[d]       + bhh[d];
    float gf = g[128 + d] + bih[128 + d] + bhh[128 + d];
    float gg = g[256 + d] + bih[256 + d] + bhh[256 + d];
    float go = g[384 + d] + bih[384 + d] + bhh[384 + d];
    float iv = 1.f / (1.f + expf(-gi));
    float fv = 1.f / (1.f + expf(-gf));
    float gv = tanhf(gg);
    float ov = 1.f / (1.f + expf(-go));
    float c  = fv * cbuf[idx] + iv * gv;
    float h  = ov * tanhf(c);
    cbuf[idx] = c;
    hbuf[idx] = h;
    qstar[(size_t)b * 256 + d] = h;
    __hip_bfloat16 hb = __float2bfloat16(h);
    abuf[(size_t)b * 384 + d] = hb;
    abuf[(size_t)b * 384 + 256 + d] = hb;
}

// ---------------------------------------------------------------------------
// Fused attention (unchanged from r1) + bf16 r store into abuf cols [128,256).
// ---------------------------------------------------------------------------
__global__ __launch_bounds__(128) void seg_attn_fused_k(
    const float* __restrict__ x, const int* __restrict__ seg,
    const float* __restrict__ hbuf, float* __restrict__ qstar,
    __hip_bfloat16* __restrict__ abuf)
{
    const int b   = blockIdx.x;
    const int ns  = seg[b], ne = seg[b + 1];
    const int tid = threadIdx.x;
    const int lane = tid & 15, grp = tid >> 4;

    __shared__ float es[CAP];
    __shared__ float red[2];

    const float4* hp = (const float4*)(hbuf + (size_t)b * DIM);
    const float4 h0 = hp[lane];
    const float4 h1 = hp[lane + 16];

    float m = -INFINITY, den = 0.f, r = 0.f;

    for (int c0 = ns; c0 < ne; c0 += CAP) {
        const int cc = min(CAP, ne - c0);

        __syncthreads();
        for (int j = c0 + grp; j < c0 + cc; j += 8) {
            const float4* xp = (const float4*)(x + (size_t)j * DIM);
            float4 xa = xp[lane], xb = xp[lane + 16];
            float s = xa.x*h0.x + xa.y*h0.y + xa.z*h0.z + xa.w*h0.w
                    + xb.x*h1.x + xb.y*h1.y + xb.z*h1.z + xb.w*h1.w;
            s += __shfl_xor(s, 1);
            s += __shfl_xor(s, 2);
            s += __shfl_xor(s, 4);
            s += __shfl_xor(s, 8);
            if (lane == 0) es[j - c0] = s;
        }
        __syncthreads();

        float cm = -INFINITY;
        for (int i = tid; i < cc; i += 128) cm = fmaxf(cm, es[i]);
        #pragma unroll
        for (int o = 1; o < 64; o <<= 1) cm = fmaxf(cm, __shfl_xor(cm, o));
        if ((tid & 63) == 0) red[tid >> 6] = cm;
        __syncthreads();
        cm = fmaxf(red[0], red[1]);
        __syncthreads();

        const float mn = fmaxf(m, cm);
        const float scale = expf(m - mn);

        float cd = 0.f;
        for (int i = tid; i < cc; i += 128) {
            float v = expf(es[i] - mn);
            es[i] = v;
            cd += v;
        }
        #pragma unroll
        for (int o = 1; o < 64; o <<= 1) cd += __shfl_xor(cd, o);
        if ((tid & 63) == 0) red[tid >> 6] = cd;
        __syncthreads();
        cd = red[0] + red[1];
        __syncthreads();

        den = den * scale + cd;
        r  *= scale;

        const float* xb2 = x + (size_t)c0 * DIM + tid;
        int jj = 0;
        for (; jj + 3 < cc; jj += 4) {
            float w0 = es[jj], w1 = es[jj+1], w2 = es[jj+2], w3 = es[jj+3];
            r = fmaf(w0, xb2[(size_t)(jj+0) * DIM], r);
            r = fmaf(w1, xb2[(size_t)(jj+1) * DIM], r);
            r = fmaf(w2, xb2[(size_t)(jj+2) * DIM], r);
            r = fmaf(w3, xb2[(size_t)(jj+3) * DIM], r);
        }
        for (; jj < cc; ++jj) r = fmaf(es[jj], xb2[(size_t)jj * DIM], r);

        m = mn;
    }

    float rv = r / (den + 1e-16f);
    qstar[(size_t)b * 256 + DIM + tid] = rv;
    abuf[(size_t)b * 384 + 128 + tid] = __float2bfloat16(rv);
}

// ---------------------------------------------------------------------------
extern "C" void kernel_launch(void* const* d_in, const int* in_sizes, int n_in,
                              void* d_out, int out_size, void* d_ws, size_t ws_size,
                              hipStream_t stream) {
    const float* x     = (const float*)d_in[0];
    const int*   batch = (const int*)d_in[1];
    const float* Wih   = (const float*)d_in[2];
    const float* Whh   = (const float*)d_in[3];
    const float* bih   = (const float*)d_in[4];
    const float* bhh   = (const float*)d_in[5];
    float* out = (float*)d_out;

    // workspace layout
    float* hbuf  = (float*)d_ws;                            // 8192*128 f32
    float* cbuf  = hbuf  + (size_t)NSEG * DIM;
    float* gates = cbuf  + (size_t)NSEG * DIM;              // 8192*512 f32
    __hip_bfloat16* abuf = (__hip_bfloat16*)(gates + (size_t)NSEG * 512);  // 8192*384
    __hip_bfloat16* wbuf = abuf + (size_t)NSEG * 384;       // 512*384
    int* seg = (int*)(wbuf + (size_t)512 * 384);

    hipMemsetAsync(hbuf, 0, (size_t)NSEG * DIM * sizeof(float), stream);
    hipMemsetAsync(cbuf, 0, (size_t)NSEG * DIM * sizeof(float), stream);
    hipMemsetAsync(abuf, 0, (size_t)NSEG * 384 * sizeof(__hip_bfloat16), stream);
    hipMemsetAsync(out,  0, (size_t)NSEG * 2 * DIM * sizeof(float), stream);

    seg_bounds_k<<<(NSEG + 256) / 256, 256, 0, stream>>>(batch, seg, NNODES);
    wconv_k<<<(512 * 384) / 256, 256, 0, stream>>>(Wih, Whh, wbuf);

    dim3 ggrid(512 / 64, NSEG / 128);   // (8, 64)
    for (int t = 0; t < TSTEPS; ++t) {
        gemm_mfma_k<<<ggrid, 256, 0, stream>>>(abuf, wbuf, gates);
        lstm_cell_k<<<(NSEG * DIM) / 256, 256, 0, stream>>>(gates, bih, bhh, cbuf, hbuf, out, abuf);
        seg_attn_fused_k<<<NSEG, 128, 0, stream>>>(x, seg, hbuf, out, abuf);
    }
}

// Round 5
// 600.973 us; speedup vs baseline: 1.4158x; 1.1910x over previous
//
#include <hip/hip_runtime.h>
#include <hip/hip_bf16.h>
#include <cstddef>
#include <cstdint>

#define NNODES 500000
#define DIM    128
#define NSEG   8192
#define TSTEPS 6
#define CCHUNK 96      // LDS-staged rows per chunk (max seg ~95 for this input)

typedef __attribute__((ext_vector_type(8))) short bf16x8;
typedef __attribute__((ext_vector_type(4))) float f32x4;
typedef unsigned short ushort_t;

static __device__ inline ushort_t f2bf_u(float f) {
    __hip_bfloat16 h = __float2bfloat16(f);
    return *reinterpret_cast<ushort_t*>(&h);
}
static __device__ inline float bfu2f(ushort_t u) {
    union { unsigned i; float f; } c; c.i = ((unsigned)u) << 16; return c.f;
}

// ---------------------------------------------------------------------------
// Segment bounds: batch is sorted; seg[b] = lower_bound(batch, b), seg[B] = N.
// ---------------------------------------------------------------------------
__global__ void seg_bounds_k(const int* __restrict__ batch, int* __restrict__ seg, int n) {
    int b = blockIdx.x * blockDim.x + threadIdx.x;
    if (b > NSEG) return;
    int lo = 0, hi = n;
    while (lo < hi) {
        int mid = (lo + hi) >> 1;
        if (batch[mid] < b) lo = mid + 1; else hi = mid;
    }
    seg[b] = lo;
}

// ---------------------------------------------------------------------------
// One-time: wbuf[n][k] bf16, k<256 from Wih[n][k], else Whh[n][k-256].
// ---------------------------------------------------------------------------
__global__ __launch_bounds__(256) void wconv_k(
    const float* __restrict__ Wih, const float* __restrict__ Whh,
    __hip_bfloat16* __restrict__ wbuf)
{
    int idx = blockIdx.x * 256 + threadIdx.x;    // 512*384 exact
    int n = idx / 384, k = idx - n * 384;
    float v = (k < 256) ? Wih[n * 256 + k] : Whh[n * 128 + (k - 256)];
    wbuf[idx] = __float2bfloat16(v);
}

// ---------------------------------------------------------------------------
// gates = Abf @ Wbf^T  (fp32 accumulate). A=[8192][384] bf16 = [q|r|h],
// W=[512][384] bf16. MFMA 16x16x32, BM=128 BN=64 BK=64, 4 waves (2x2),
// XOR-swizzled LDS, issue-early staging.
// ---------------------------------------------------------------------------
__global__ __launch_bounds__(256) void gemm_mfma_k(
    const __hip_bfloat16* __restrict__ abuf,
    const __hip_bfloat16* __restrict__ wbuf,
    float* __restrict__ gates)
{
    __shared__ char As[128 * 128];
    __shared__ char Bs[64 * 128];
    const int tid  = threadIdx.x;
    const int lane = tid & 63, wave = tid >> 6;
    const int wrow = (wave >> 1) * 64;
    const int wcol = (wave & 1) * 32;
    const int m0 = blockIdx.y * 128;
    const int n0 = blockIdx.x * 64;

    const int ar  = tid >> 1;
    const int acb = (tid & 1) * 64;
    const int br  = tid >> 2;
    const int bcb = (tid & 3) * 32;

    const char* aP = (const char*)(abuf + (size_t)(m0 + ar) * 384) + acb;
    const char* bP = (const char*)(wbuf + (size_t)(n0 + br) * 384) + bcb;

    f32x4 acc[4][2] = {};

    int4 ra[4]; int4 rb2[2];
    #pragma unroll
    for (int c = 0; c < 4; ++c) ra[c]  = *(const int4*)(aP + c * 16);
    #pragma unroll
    for (int c = 0; c < 2; ++c) rb2[c] = *(const int4*)(bP + c * 16);

    char* asw = As + ar * 128;
    char* bsw = Bs + br * 128;
    const int amask = (ar & 7) << 4;
    const int bmask = (br & 7) << 4;

    for (int s = 0; s < 6; ++s) {
        __syncthreads();
        #pragma unroll
        for (int c = 0; c < 4; ++c)
            *(int4*)(asw + ((acb + c * 16) ^ amask)) = ra[c];
        #pragma unroll
        for (int c = 0; c < 2; ++c)
            *(int4*)(bsw + ((bcb + c * 16) ^ bmask)) = rb2[c];
        __syncthreads();

        if (s < 5) {
            const char* aN = aP + (size_t)(s + 1) * 128;
            const char* bN = bP + (size_t)(s + 1) * 128;
            #pragma unroll
            for (int c = 0; c < 4; ++c) ra[c]  = *(const int4*)(aN + c * 16);
            #pragma unroll
            for (int c = 0; c < 2; ++c) rb2[c] = *(const int4*)(bN + c * 16);
        }

        #pragma unroll
        for (int ks = 0; ks < 2; ++ks) {
            const int kb = ks * 64 + ((lane >> 4) << 4);
            bf16x8 af[4], bfr[2];
            #pragma unroll
            for (int rbk = 0; rbk < 4; ++rbk) {
                int r = wrow + rbk * 16 + (lane & 15);
                af[rbk] = *(const bf16x8*)(As + r * 128 + (kb ^ ((r & 7) << 4)));
            }
            #pragma unroll
            for (int cb = 0; cb < 2; ++cb) {
                int n = wcol + cb * 16 + (lane & 15);
                bfr[cb] = *(const bf16x8*)(Bs + n * 128 + (kb ^ ((n & 7) << 4)));
            }
            #pragma unroll
            for (int rbk = 0; rbk < 4; ++rbk)
                #pragma unroll
                for (int cb = 0; cb < 2; ++cb)
                    acc[rbk][cb] = __builtin_amdgcn_mfma_f32_16x16x32_bf16(
                        af[rbk], bfr[cb], acc[rbk][cb], 0, 0, 0);
        }
    }

    const int rowb = (lane >> 4) << 2;
    const int coll = lane & 15;
    #pragma unroll
    for (int rbk = 0; rbk < 4; ++rbk)
        #pragma unroll
        for (int cb = 0; cb < 2; ++cb) {
            int row = m0 + wrow + rbk * 16 + rowb;
            int col = n0 + wcol + cb * 16 + coll;
            float* gp = gates + (size_t)row * 512 + col;
            #pragma unroll
            for (int reg = 0; reg < 4; ++reg)
                gp[(size_t)reg * 512] = acc[rbk][cb][reg];
        }
}

// ---------------------------------------------------------------------------
// LSTM cell elementwise; writes q=h to d_out[:,0:128], h to abuf cols [0,128)
// and [256,384) (bf16), plus fp32 hbuf/cbuf.
// ---------------------------------------------------------------------------
__global__ __launch_bounds__(256) void lstm_cell_k(
    const float* __restrict__ gates, const float* __restrict__ bih,
    const float* __restrict__ bhh,   float* __restrict__ cbuf,
    float* __restrict__ hbuf,        float* __restrict__ qstar,
    __hip_bfloat16* __restrict__ abuf)
{
    int idx = blockIdx.x * 256 + threadIdx.x;   // b*128 + d
    int b = idx >> 7, d = idx & 127;
    const float* g = gates + (size_t)b * 512;
    float gi = g[d]       + bih[d]       + bhh[d];
    float gf = g[128 + d] + bih[128 + d] + bhh[128 + d];
    float gg = g[256 + d] + bih[256 + d] + bhh[256 + d];
    float go = g[384 + d] + bih[384 + d] + bhh[384 + d];
    float iv = 1.f / (1.f + expf(-gi));
    float fv = 1.f / (1.f + expf(-gf));
    float gv = tanhf(gg);
    float ov = 1.f / (1.f + expf(-go));
    float c  = fv * cbuf[idx] + iv * gv;
    float h  = ov * tanhf(c);
    cbuf[idx] = c;
    hbuf[idx] = h;
    qstar[(size_t)b * 256 + d] = h;
    __hip_bfloat16 hb = __float2bfloat16(h);
    abuf[(size_t)b * 384 + d] = hb;
    abuf[(size_t)b * 384 + 256 + d] = hb;
}

// ---------------------------------------------------------------------------
// Fused attention with LDS x-staging: pass1 computes e from fp32 x (exact
// softmax weights) AND stages the row into LDS as bf16; pass3 reads LDS only.
// Global x traffic: one pass per step instead of two.
// ---------------------------------------------------------------------------
__global__ __launch_bounds__(128) void seg_attn_fused_k(
    const float* __restrict__ x, const int* __restrict__ seg,
    const float* __restrict__ hbuf, float* __restrict__ qstar,
    __hip_bfloat16* __restrict__ abuf)
{
    const int b   = blockIdx.x;
    const int ns  = seg[b], ne = seg[b + 1];
    const int tid = threadIdx.x;
    const int lane = tid & 15, grp = tid >> 4;

    __shared__ ushort_t xs[CCHUNK * 128];   // bf16 rows, 24 KB
    __shared__ float es[CCHUNK];
    __shared__ float red[2];

    const float4* hp = (const float4*)(hbuf + (size_t)b * DIM);
    const float4 h0 = hp[lane];
    const float4 h1 = hp[lane + 16];

    float m = -INFINITY, den = 0.f, r = 0.f;

    for (int c0 = ns; c0 < ne; c0 += CCHUNK) {
        const int cc = min(CCHUNK, ne - c0);

        __syncthreads();   // prior chunk's xs/es readers done
        // pass 1: e + LDS staging; 8 nodes in flight (one per 16-lane group)
        for (int j = c0 + grp; j < c0 + cc; j += 8) {
            const float4* xp = (const float4*)(x + (size_t)j * DIM);
            float4 xa = xp[lane], xb = xp[lane + 16];
            float s = xa.x*h0.x + xa.y*h0.y + xa.z*h0.z + xa.w*h0.w
                    + xb.x*h1.x + xb.y*h1.y + xb.z*h1.z + xb.w*h1.w;
            s += __shfl_xor(s, 1);
            s += __shfl_xor(s, 2);
            s += __shfl_xor(s, 4);
            s += __shfl_xor(s, 8);
            const int row = j - c0;
            // stage row as bf16: dims [4*lane,4*lane+4) and [64+4*lane, ...)
            uint2 pa, pb;
            pa.x = (unsigned)f2bf_u(xa.x) | ((unsigned)f2bf_u(xa.y) << 16);
            pa.y = (unsigned)f2bf_u(xa.z) | ((unsigned)f2bf_u(xa.w) << 16);
            pb.x = (unsigned)f2bf_u(xb.x) | ((unsigned)f2bf_u(xb.y) << 16);
            pb.y = (unsigned)f2bf_u(xb.z) | ((unsigned)f2bf_u(xb.w) << 16);
            *(uint2*)(&xs[row * 128 + 4 * lane])      = pa;
            *(uint2*)(&xs[row * 128 + 64 + 4 * lane]) = pb;
            if (lane == 0) es[row] = s;
        }
        __syncthreads();

        // chunk max
        float cm = -INFINITY;
        for (int i = tid; i < cc; i += 128) cm = fmaxf(cm, es[i]);
        #pragma unroll
        for (int o = 1; o < 64; o <<= 1) cm = fmaxf(cm, __shfl_xor(cm, o));
        if ((tid & 63) == 0) red[tid >> 6] = cm;
        __syncthreads();
        cm = fmaxf(red[0], red[1]);
        __syncthreads();

        const float mn = fmaxf(m, cm);
        const float scale = expf(m - mn);   // m=-inf on first chunk -> 0

        // exp in place + chunk denom
        float cd = 0.f;
        for (int i = tid; i < cc; i += 128) {
            float v = expf(es[i] - mn);
            es[i] = v;
            cd += v;
        }
        #pragma unroll
        for (int o = 1; o < 64; o <<= 1) cd += __shfl_xor(cd, o);
        if ((tid & 63) == 0) red[tid >> 6] = cd;
        __syncthreads();
        cd = red[0] + red[1];
        __syncthreads();

        den = den * scale + cd;
        r  *= scale;

        // pass 3: weighted sum from LDS (thread tid owns dim tid)
        const ushort_t* xr = xs + tid;
        int jj = 0;
        for (; jj + 3 < cc; jj += 4) {
            float w0 = es[jj], w1 = es[jj+1], w2 = es[jj+2], w3 = es[jj+3];
            r = fmaf(w0, bfu2f(xr[(jj+0) * 128]), r);
            r = fmaf(w1, bfu2f(xr[(jj+1) * 128]), r);
            r = fmaf(w2, bfu2f(xr[(jj+2) * 128]), r);
            r = fmaf(w3, bfu2f(xr[(jj+3) * 128]), r);
        }
        for (; jj < cc; ++jj) r = fmaf(es[jj], bfu2f(xr[jj * 128]), r);

        m = mn;
    }

    float rv = r / (den + 1e-16f);
    qstar[(size_t)b * 256 + DIM + tid] = rv;
    abuf[(size_t)b * 384 + 128 + tid] = __float2bfloat16(rv);
}

// ---------------------------------------------------------------------------
extern "C" void kernel_launch(void* const* d_in, const int* in_sizes, int n_in,
                              void* d_out, int out_size, void* d_ws, size_t ws_size,
                              hipStream_t stream) {
    const float* x     = (const float*)d_in[0];
    const int*   batch = (const int*)d_in[1];
    const float* Wih   = (const float*)d_in[2];
    const float* Whh   = (const float*)d_in[3];
    const float* bih   = (const float*)d_in[4];
    const float* bhh   = (const float*)d_in[5];
    float* out = (float*)d_out;

    // workspace layout
    float* hbuf  = (float*)d_ws;                            // 8192*128 f32
    float* cbuf  = hbuf  + (size_t)NSEG * DIM;
    float* gates = cbuf  + (size_t)NSEG * DIM;              // 8192*512 f32
    __hip_bfloat16* abuf = (__hip_bfloat16*)(gates + (size_t)NSEG * 512);  // 8192*384
    __hip_bfloat16* wbuf = abuf + (size_t)NSEG * 384;       // 512*384
    int* seg = (int*)(wbuf + (size_t)512 * 384);

    hipMemsetAsync(hbuf, 0, (size_t)NSEG * DIM * sizeof(float), stream);
    hipMemsetAsync(cbuf, 0, (size_t)NSEG * DIM * sizeof(float), stream);
    hipMemsetAsync(abuf, 0, (size_t)NSEG * 384 * sizeof(__hip_bfloat16), stream);
    hipMemsetAsync(out,  0, (size_t)NSEG * 2 * DIM * sizeof(float), stream);

    seg_bounds_k<<<(NSEG + 256) / 256, 256, 0, stream>>>(batch, seg, NNODES);
    wconv_k<<<(512 * 384) / 256, 256, 0, stream>>>(Wih, Whh, wbuf);

    dim3 ggrid(512 / 64, NSEG / 128);   // (8, 64)
    for (int t = 0; t < TSTEPS; ++t) {
        gemm_mfma_k<<<ggrid, 256, 0, stream>>>(abuf, wbuf, gates);
        lstm_cell_k<<<(NSEG * DIM) / 256, 256, 0, stream>>>(gates, bih, bhh, cbuf, hbuf, out, abuf);
        seg_attn_fused_k<<<NSEG, 128, 0, stream>>>(x, seg, hbuf, out, abuf);
    }
}

// Round 7
// 537.646 us; speedup vs baseline: 1.5826x; 1.1178x over previous
//
#include <hip/hip_runtime.h>
#include <hip/hip_bf16.h>
#include <cstddef>
#include <cstdint>

#define NNODES 500000
#define DIM    128
#define NSEG   8192
#define TSTEPS 6
#define CCHUNK 96      // LDS-staged rows per chunk (max seg ~95 for this input)

typedef __attribute__((ext_vector_type(8))) short bf16x8;
typedef __attribute__((ext_vector_type(4))) float f32x4;
typedef unsigned short ushort_t;

static __device__ inline ushort_t f2bf_u(float f) {
    __hip_bfloat16 h = __float2bfloat16(f);
    return *reinterpret_cast<ushort_t*>(&h);
}
static __device__ inline float bfu2f(ushort_t u) {
    union { unsigned i; float f; } c; c.i = ((unsigned)u) << 16; return c.f;
}

// ---------------------------------------------------------------------------
// Segment bounds: batch is sorted; seg[b] = lower_bound(batch, b), seg[B] = N.
// ---------------------------------------------------------------------------
__global__ void seg_bounds_k(const int* __restrict__ batch, int* __restrict__ seg, int n) {
    int b = blockIdx.x * blockDim.x + threadIdx.x;
    if (b > NSEG) return;
    int lo = 0, hi = n;
    while (lo < hi) {
        int mid = (lo + hi) >> 1;
        if (batch[mid] < b) lo = mid + 1; else hi = mid;
    }
    seg[b] = lo;
}

// ---------------------------------------------------------------------------
// One-time: wbuf[n][k] bf16, k<256 from Wih[n][k], else Whh[n][k-256].
// ---------------------------------------------------------------------------
__global__ __launch_bounds__(256) void wconv_k(
    const float* __restrict__ Wih, const float* __restrict__ Whh,
    __hip_bfloat16* __restrict__ wbuf)
{
    int idx = blockIdx.x * 256 + threadIdx.x;    // 512*384 exact
    int n = idx / 384, k = idx - n * 384;
    float v = (k < 256) ? Wih[n * 256 + k] : Whh[n * 128 + (k - 256)];
    wbuf[idx] = __float2bfloat16(v);
}

// ---------------------------------------------------------------------------
// gates = Abf @ Wbf^T  (fp32 accumulate). A=[8192][384] bf16 = [q|r|h],
// W=[512][384] bf16. MFMA 16x16x32, BM=128 BN=64 BK=64, 4 waves (2x2),
// XOR-swizzled LDS, issue-early staging.
// ---------------------------------------------------------------------------
__global__ __launch_bounds__(256) void gemm_mfma_k(
    const __hip_bfloat16* __restrict__ abuf,
    const __hip_bfloat16* __restrict__ wbuf,
    float* __restrict__ gates)
{
    __shared__ char As[128 * 128];
    __shared__ char Bs[64 * 128];
    const int tid  = threadIdx.x;
    const int lane = tid & 63, wave = tid >> 6;
    const int wrow = (wave >> 1) * 64;
    const int wcol = (wave & 1) * 32;
    const int m0 = blockIdx.y * 128;
    const int n0 = blockIdx.x * 64;

    const int ar  = tid >> 1;
    const int acb = (tid & 1) * 64;
    const int br  = tid >> 2;
    const int bcb = (tid & 3) * 32;

    const char* aP = (const char*)(abuf + (size_t)(m0 + ar) * 384) + acb;
    const char* bP = (const char*)(wbuf + (size_t)(n0 + br) * 384) + bcb;

    f32x4 acc[4][2] = {};

    int4 ra[4]; int4 rb2[2];
    #pragma unroll
    for (int c = 0; c < 4; ++c) ra[c]  = *(const int4*)(aP + c * 16);
    #pragma unroll
    for (int c = 0; c < 2; ++c) rb2[c] = *(const int4*)(bP + c * 16);

    char* asw = As + ar * 128;
    char* bsw = Bs + br * 128;
    const int amask = (ar & 7) << 4;
    const int bmask = (br & 7) << 4;

    for (int s = 0; s < 6; ++s) {
        __syncthreads();
        #pragma unroll
        for (int c = 0; c < 4; ++c)
            *(int4*)(asw + ((acb + c * 16) ^ amask)) = ra[c];
        #pragma unroll
        for (int c = 0; c < 2; ++c)
            *(int4*)(bsw + ((bcb + c * 16) ^ bmask)) = rb2[c];
        __syncthreads();

        if (s < 5) {
            const char* aN = aP + (size_t)(s + 1) * 128;
            const char* bN = bP + (size_t)(s + 1) * 128;
            #pragma unroll
            for (int c = 0; c < 4; ++c) ra[c]  = *(const int4*)(aN + c * 16);
            #pragma unroll
            for (int c = 0; c < 2; ++c) rb2[c] = *(const int4*)(bN + c * 16);
        }

        #pragma unroll
        for (int ks = 0; ks < 2; ++ks) {
            const int kb = ks * 64 + ((lane >> 4) << 4);
            bf16x8 af[4], bfr[2];
            #pragma unroll
            for (int rbk = 0; rbk < 4; ++rbk) {
                int r = wrow + rbk * 16 + (lane & 15);
                af[rbk] = *(const bf16x8*)(As + r * 128 + (kb ^ ((r & 7) << 4)));
            }
            #pragma unroll
            for (int cb = 0; cb < 2; ++cb) {
                int n = wcol + cb * 16 + (lane & 15);
                bfr[cb] = *(const bf16x8*)(Bs + n * 128 + (kb ^ ((n & 7) << 4)));
            }
            #pragma unroll
            for (int rbk = 0; rbk < 4; ++rbk)
                #pragma unroll
                for (int cb = 0; cb < 2; ++cb)
                    acc[rbk][cb] = __builtin_amdgcn_mfma_f32_16x16x32_bf16(
                        af[rbk], bfr[cb], acc[rbk][cb], 0, 0, 0);
        }
    }

    const int rowb = (lane >> 4) << 2;
    const int coll = lane & 15;
    #pragma unroll
    for (int rbk = 0; rbk < 4; ++rbk)
        #pragma unroll
        for (int cb = 0; cb < 2; ++cb) {
            int row = m0 + wrow + rbk * 16 + rowb;
            int col = n0 + wcol + cb * 16 + coll;
            float* gp = gates + (size_t)row * 512 + col;
            #pragma unroll
            for (int reg = 0; reg < 4; ++reg)
                gp[(size_t)reg * 512] = acc[rbk][cb][reg];
        }
}

// ---------------------------------------------------------------------------
// LSTM cell elementwise; writes q=h to d_out[:,0:128], h to abuf cols [0,128)
// and [256,384) (bf16), plus fp32 hbuf/cbuf.
// ---------------------------------------------------------------------------
__global__ __launch_bounds__(256) void lstm_cell_k(
    const float* __restrict__ gates, const float* __restrict__ bih,
    const float* __restrict__ bhh,   float* __restrict__ cbuf,
    float* __restrict__ hbuf,        float* __restrict__ qstar,
    __hip_bfloat16* __restrict__ abuf)
{
    int idx = blockIdx.x * 256 + threadIdx.x;   // b*128 + d
    int b = idx >> 7, d = idx & 127;
    const float* g = gates + (size_t)b * 512;
    float gi = g[d]       + bih[d]       + bhh[d];
    float gf = g[128 + d] + bih[128 + d] + bhh[128 + d];
    float gg = g[256 + d] + bih[256 + d] + bhh[256 + d];
    float go = g[384 + d] + bih[384 + d] + bhh[384 + d];
    float iv = 1.f / (1.f + expf(-gi));
    float fv = 1.f / (1.f + expf(-gf));
    float gv = tanhf(gg);
    float ov = 1.f / (1.f + expf(-go));
    float c  = fv * cbuf[idx] + iv * gv;
    float h  = ov * tanhf(c);
    cbuf[idx] = c;
    hbuf[idx] = h;
    qstar[(size_t)b * 256 + d] = h;
    __hip_bfloat16 hb = __float2bfloat16(h);
    abuf[(size_t)b * 384 + d] = hb;
    abuf[(size_t)b * 384 + 256 + d] = hb;
}

// ---------------------------------------------------------------------------
// Fused attention. Modes (wave-uniform runtime flags):
//   read_bf=0: pass1 reads fp32 x; if write_bf, also emits bf16 x to xbf.
//   read_bf=1: pass1 reads bf16 xbf (half the traffic, L3-resident).
// Pass 3 always reads the LDS bf16 staging. e always fp32-accumulated.
// ---------------------------------------------------------------------------
__global__ __launch_bounds__(128) void seg_attn_fused_k(
    const float* __restrict__ x, ushort_t* __restrict__ xbf,
    const int* __restrict__ seg, const float* __restrict__ hbuf,
    float* __restrict__ qstar, __hip_bfloat16* __restrict__ abuf,
    int read_bf, int write_bf)
{
    const int b   = blockIdx.x;
    const int ns  = seg[b], ne = seg[b + 1];
    const int tid = threadIdx.x;
    const int lane = tid & 15, grp = tid >> 4;

    __shared__ ushort_t xs[CCHUNK * 128];   // bf16 rows, 24 KB
    __shared__ float es[CCHUNK];
    __shared__ float red[2];

    const float4* hp = (const float4*)(hbuf + (size_t)b * DIM);
    // fp32-path fragment: dims [4*lane,+4) and [64+4*lane,+4)
    const float4 h0 = hp[lane];
    const float4 h1 = hp[lane + 16];
    // bf16-path fragment: dims [8*lane, +8)
    const float4 hA = hp[2 * lane];
    const float4 hB = hp[2 * lane + 1];

    float m = -INFINITY, den = 0.f, r = 0.f;

    for (int c0 = ns; c0 < ne; c0 += CCHUNK) {
        const int cc = min(CCHUNK, ne - c0);

        __syncthreads();   // prior chunk's xs/es readers done
        if (read_bf) {
            // pass 1 (bf16): one int4 = 8 bf16 per lane; stage raw
            for (int j = c0 + grp; j < c0 + cc; j += 8) {
                const int row = j - c0;
                int4 v = *(const int4*)(xbf + (size_t)j * 128 + 8 * lane);
                *(int4*)(&xs[row * 128 + 8 * lane]) = v;
                const ushort_t* u = (const ushort_t*)&v;
                float s = bfu2f(u[0])*hA.x + bfu2f(u[1])*hA.y
                        + bfu2f(u[2])*hA.z + bfu2f(u[3])*hA.w
                        + bfu2f(u[4])*hB.x + bfu2f(u[5])*hB.y
                        + bfu2f(u[6])*hB.z + bfu2f(u[7])*hB.w;
                s += __shfl_xor(s, 1);
                s += __shfl_xor(s, 2);
                s += __shfl_xor(s, 4);
                s += __shfl_xor(s, 8);
                if (lane == 0) es[row] = s;
            }
        } else {
            // pass 1 (fp32): exact e; stage bf16; optionally emit xbf
            for (int j = c0 + grp; j < c0 + cc; j += 8) {
                const int row = j - c0;
                const float4* xp = (const float4*)(x + (size_t)j * DIM);
                float4 xa = xp[lane], xb = xp[lane + 16];
                float s = xa.x*h0.x + xa.y*h0.y + xa.z*h0.z + xa.w*h0.w
                        + xb.x*h1.x + xb.y*h1.y + xb.z*h1.z + xb.w*h1.w;
                s += __shfl_xor(s, 1);
                s += __shfl_xor(s, 2);
                s += __shfl_xor(s, 4);
                s += __shfl_xor(s, 8);
                uint2 pa, pb;
                pa.x = (unsigned)f2bf_u(xa.x) | ((unsigned)f2bf_u(xa.y) << 16);
                pa.y = (unsigned)f2bf_u(xa.z) | ((unsigned)f2bf_u(xa.w) << 16);
                pb.x = (unsigned)f2bf_u(xb.x) | ((unsigned)f2bf_u(xb.y) << 16);
                pb.y = (unsigned)f2bf_u(xb.z) | ((unsigned)f2bf_u(xb.w) << 16);
                *(uint2*)(&xs[row * 128 + 4 * lane])      = pa;
                *(uint2*)(&xs[row * 128 + 64 + 4 * lane]) = pb;
                if (write_bf) {
                    *(uint2*)(xbf + (size_t)j * 128 + 4 * lane)      = pa;
                    *(uint2*)(xbf + (size_t)j * 128 + 64 + 4 * lane) = pb;
                }
                if (lane == 0) es[row] = s;
            }
        }
        __syncthreads();

        // chunk max
        float cm = -INFINITY;
        for (int i = tid; i < cc; i += 128) cm = fmaxf(cm, es[i]);
        #pragma unroll
        for (int o = 1; o < 64; o <<= 1) cm = fmaxf(cm, __shfl_xor(cm, o));
        if ((tid & 63) == 0) red[tid >> 6] = cm;
        __syncthreads();
        cm = fmaxf(red[0], red[1]);
        __syncthreads();

        const float mn = fmaxf(m, cm);
        const float scale = expf(m - mn);   // m=-inf on first chunk -> 0

        // exp in place + chunk denom
        float cd = 0.f;
        for (int i = tid; i < cc; i += 128) {
            float v = expf(es[i] - mn);
            es[i] = v;
            cd += v;
        }
        #pragma unroll
        for (int o = 1; o < 64; o <<= 1) cd += __shfl_xor(cd, o);
        if ((tid & 63) == 0) red[tid >> 6] = cd;
        __syncthreads();
        cd = red[0] + red[1];
        __syncthreads();

        den = den * scale + cd;
        r  *= scale;

        // pass 3: weighted sum from LDS (thread tid owns dim tid)
        const ushort_t* xr = xs + tid;
        int jj = 0;
        for (; jj + 3 < cc; jj += 4) {
            float w0 = es[jj], w1 = es[jj+1], w2 = es[jj+2], w3 = es[jj+3];
            r = fmaf(w0, bfu2f(xr[(jj+0) * 128]), r);
            r = fmaf(w1, bfu2f(xr[(jj+1) * 128]), r);
            r = fmaf(w2, bfu2f(xr[(jj+2) * 128]), r);
            r = fmaf(w3, bfu2f(xr[(jj+3) * 128]), r);
        }
        for (; jj < cc; ++jj) r = fmaf(es[jj], bfu2f(xr[jj * 128]), r);

        m = mn;
    }

    float rv = r / (den + 1e-16f);
    qstar[(size_t)b * 256 + DIM + tid] = rv;
    abuf[(size_t)b * 384 + 128 + tid] = __float2bfloat16(rv);
}

// ---------------------------------------------------------------------------
extern "C" void kernel_launch(void* const* d_in, const int* in_sizes, int n_in,
                              void* d_out, int out_size, void* d_ws, size_t ws_size,
                              hipStream_t stream) {
    const float* x     = (const float*)d_in[0];
    const int*   batch = (const int*)d_in[1];
    const float* Wih   = (const float*)d_in[2];
    const float* Whh   = (const float*)d_in[3];
    const float* bih   = (const float*)d_in[4];
    const float* bhh   = (const float*)d_in[5];
    float* out = (float*)d_out;

    // workspace layout
    float* hbuf  = (float*)d_ws;                            // 8192*128 f32
    float* cbuf  = hbuf  + (size_t)NSEG * DIM;
    float* gates = cbuf  + (size_t)NSEG * DIM;              // 8192*512 f32
    __hip_bfloat16* abuf = (__hip_bfloat16*)(gates + (size_t)NSEG * 512);  // 8192*384
    __hip_bfloat16* wbuf = abuf + (size_t)NSEG * 384;       // 512*384
    int* seg = (int*)(wbuf + (size_t)512 * 384);
    // xbf after seg, 16-B aligned
    size_t fixed_bytes = (size_t)((char*)(seg + NSEG + 1) - (char*)d_ws);
    size_t xbf_off = (fixed_bytes + 15) & ~(size_t)15;
    ushort_t* xbf = (ushort_t*)((char*)d_ws + xbf_off);
    size_t need = xbf_off + (size_t)NNODES * DIM * sizeof(ushort_t);
    const int use_xbf = (ws_size >= need) ? 1 : 0;

    hipMemsetAsync(hbuf, 0, (size_t)NSEG * DIM * sizeof(float), stream);
    hipMemsetAsync(cbuf, 0, (size_t)NSEG * DIM * sizeof(float), stream);
    hipMemsetAsync(abuf, 0, (size_t)NSEG * 384 * sizeof(__hip_bfloat16), stream);
    hipMemsetAsync(out,  0, (size_t)NSEG * 2 * DIM * sizeof(float), stream);

    seg_bounds_k<<<(NSEG + 256) / 256, 256, 0, stream>>>(batch, seg, NNODES);
    wconv_k<<<(512 * 384) / 256, 256, 0, stream>>>(Wih, Whh, wbuf);

    dim3 ggrid(512 / 64, NSEG / 128);   // (8, 64)
    for (int t = 0; t < TSTEPS; ++t) {
        gemm_mfma_k<<<ggrid, 256, 0, stream>>>(abuf, wbuf, gates);
        lstm_cell_k<<<(NSEG * DIM) / 256, 256, 0, stream>>>(gates, bih, bhh, cbuf, hbuf, out, abuf);
        const int read_bf  = (use_xbf && t > 0) ? 1 : 0;
        const int write_bf = (use_xbf && t == 0) ? 1 : 0;
        seg_attn_fused_k<<<NSEG, 128, 0, stream>>>(x, xbf, seg, hbuf, out, abuf,
                                                   read_bf, write_bf);
    }
}

// Round 8
// 490.469 us; speedup vs baseline: 1.7348x; 1.0962x over previous
//
#include <hip/hip_runtime.h>
#include <hip/hip_bf16.h>
#include <cstddef>
#include <cstdint>

#define NNODES 500000
#define DIM    128
#define NSEG   8192
#define TSTEPS 6
#define WCHUNK 32      // rows staged per wave-chunk

typedef __attribute__((ext_vector_type(8))) short bf16x8;
typedef __attribute__((ext_vector_type(4))) float f32x4;
typedef unsigned short ushort_t;

static __device__ inline ushort_t f2bf_u(float f) {
    __hip_bfloat16 h = __float2bfloat16(f);
    return *reinterpret_cast<ushort_t*>(&h);
}
static __device__ inline float bfu2f(ushort_t u) {
    union { unsigned i; float f; } c; c.i = ((unsigned)u) << 16; return c.f;
}
#define LGKM_WAIT() __asm__ __volatile__("s_waitcnt lgkmcnt(0)" ::: "memory")

// ---------------------------------------------------------------------------
// Segment bounds: batch is sorted; seg[b] = lower_bound(batch, b), seg[B] = N.
// ---------------------------------------------------------------------------
__global__ void seg_bounds_k(const int* __restrict__ batch, int* __restrict__ seg, int n) {
    int b = blockIdx.x * blockDim.x + threadIdx.x;
    if (b > NSEG) return;
    int lo = 0, hi = n;
    while (lo < hi) {
        int mid = (lo + hi) >> 1;
        if (batch[mid] < b) lo = mid + 1; else hi = mid;
    }
    seg[b] = lo;
}

// ---------------------------------------------------------------------------
// One-time: wbuf[n][k] bf16, k<256 from Wih[n][k], else Whh[n][k-256].
// ---------------------------------------------------------------------------
__global__ __launch_bounds__(256) void wconv_k(
    const float* __restrict__ Wih, const float* __restrict__ Whh,
    __hip_bfloat16* __restrict__ wbuf)
{
    int idx = blockIdx.x * 256 + threadIdx.x;    // 512*384 exact
    int n = idx / 384, k = idx - n * 384;
    float v = (k < 256) ? Wih[n * 256 + k] : Whh[n * 128 + (k - 256)];
    wbuf[idx] = __float2bfloat16(v);
}

// ---------------------------------------------------------------------------
// gates = Abf @ Wbf^T  (fp32 accumulate). A=[8192][384] bf16 = [q|r|h],
// W=[512][384] bf16. MFMA 16x16x32, BM=128 BN=64 BK=64, 4 waves (2x2).
// ---------------------------------------------------------------------------
__global__ __launch_bounds__(256) void gemm_mfma_k(
    const __hip_bfloat16* __restrict__ abuf,
    const __hip_bfloat16* __restrict__ wbuf,
    float* __restrict__ gates)
{
    __shared__ char As[128 * 128];
    __shared__ char Bs[64 * 128];
    const int tid  = threadIdx.x;
    const int lane = tid & 63, wave = tid >> 6;
    const int wrow = (wave >> 1) * 64;
    const int wcol = (wave & 1) * 32;
    const int m0 = blockIdx.y * 128;
    const int n0 = blockIdx.x * 64;

    const int ar  = tid >> 1;
    const int acb = (tid & 1) * 64;
    const int br  = tid >> 2;
    const int bcb = (tid & 3) * 32;

    const char* aP = (const char*)(abuf + (size_t)(m0 + ar) * 384) + acb;
    const char* bP = (const char*)(wbuf + (size_t)(n0 + br) * 384) + bcb;

    f32x4 acc[4][2] = {};

    int4 ra[4]; int4 rb2[2];
    #pragma unroll
    for (int c = 0; c < 4; ++c) ra[c]  = *(const int4*)(aP + c * 16);
    #pragma unroll
    for (int c = 0; c < 2; ++c) rb2[c] = *(const int4*)(bP + c * 16);

    char* asw = As + ar * 128;
    char* bsw = Bs + br * 128;
    const int amask = (ar & 7) << 4;
    const int bmask = (br & 7) << 4;

    for (int s = 0; s < 6; ++s) {
        __syncthreads();
        #pragma unroll
        for (int c = 0; c < 4; ++c)
            *(int4*)(asw + ((acb + c * 16) ^ amask)) = ra[c];
        #pragma unroll
        for (int c = 0; c < 2; ++c)
            *(int4*)(bsw + ((bcb + c * 16) ^ bmask)) = rb2[c];
        __syncthreads();

        if (s < 5) {
            const char* aN = aP + (size_t)(s + 1) * 128;
            const char* bN = bP + (size_t)(s + 1) * 128;
            #pragma unroll
            for (int c = 0; c < 4; ++c) ra[c]  = *(const int4*)(aN + c * 16);
            #pragma unroll
            for (int c = 0; c < 2; ++c) rb2[c] = *(const int4*)(bN + c * 16);
        }

        #pragma unroll
        for (int ks = 0; ks < 2; ++ks) {
            const int kb = ks * 64 + ((lane >> 4) << 4);
            bf16x8 af[4], bfr[2];
            #pragma unroll
            for (int rbk = 0; rbk < 4; ++rbk) {
                int r = wrow + rbk * 16 + (lane & 15);
                af[rbk] = *(const bf16x8*)(As + r * 128 + (kb ^ ((r & 7) << 4)));
            }
            #pragma unroll
            for (int cb = 0; cb < 2; ++cb) {
                int n = wcol + cb * 16 + (lane & 15);
                bfr[cb] = *(const bf16x8*)(Bs + n * 128 + (kb ^ ((n & 7) << 4)));
            }
            #pragma unroll
            for (int rbk = 0; rbk < 4; ++rbk)
                #pragma unroll
                for (int cb = 0; cb < 2; ++cb)
                    acc[rbk][cb] = __builtin_amdgcn_mfma_f32_16x16x32_bf16(
                        af[rbk], bfr[cb], acc[rbk][cb], 0, 0, 0);
        }
    }

    const int rowb = (lane >> 4) << 2;
    const int coll = lane & 15;
    #pragma unroll
    for (int rbk = 0; rbk < 4; ++rbk)
        #pragma unroll
        for (int cb = 0; cb < 2; ++cb) {
            int row = m0 + wrow + rbk * 16 + rowb;
            int col = n0 + wcol + cb * 16 + coll;
            float* gp = gates + (size_t)row * 512 + col;
            #pragma unroll
            for (int reg = 0; reg < 4; ++reg)
                gp[(size_t)reg * 512] = acc[rbk][cb][reg];
        }
}

// ---------------------------------------------------------------------------
// LSTM cell elementwise; writes q=h to d_out[:,0:128], h to abuf cols [0,128)
// and [256,384) (bf16), plus fp32 hbuf/cbuf.
// ---------------------------------------------------------------------------
__global__ __launch_bounds__(256) void lstm_cell_k(
    const float* __restrict__ gates, const float* __restrict__ bih,
    const float* __restrict__ bhh,   float* __restrict__ cbuf,
    float* __restrict__ hbuf,        float* __restrict__ qstar,
    __hip_bfloat16* __restrict__ abuf)
{
    int idx = blockIdx.x * 256 + threadIdx.x;   // b*128 + d
    int b = idx >> 7, d = idx & 127;
    const float* g = gates + (size_t)b * 512;
    float gi = g[d]       + bih[d]       + bhh[d];
    float gf = g[128 + d] + bih[128 + d] + bhh[128 + d];
    float gg = g[256 + d] + bih[256 + d] + bhh[256 + d];
    float go = g[384 + d] + bih[384 + d] + bhh[384 + d];
    float iv = 1.f / (1.f + expf(-gi));
    float fv = 1.f / (1.f + expf(-gf));
    float gv = tanhf(gg);
    float ov = 1.f / (1.f + expf(-go));
    float c  = fv * cbuf[idx] + iv * gv;
    float h  = ov * tanhf(c);
    cbuf[idx] = c;
    hbuf[idx] = h;
    qstar[(size_t)b * 256 + d] = h;
    __hip_bfloat16 hb = __float2bfloat16(h);
    abuf[(size_t)b * 384 + d] = hb;
    abuf[(size_t)b * 384 + 256 + d] = hb;
}

// ---------------------------------------------------------------------------
// Wave-per-segment fused attention. 2 waves/block, each wave owns one
// segment; NO __syncthreads (wave-synchronous; DS ops in-order per wave,
// explicit lgkmcnt fences at phase boundaries). Online softmax, WCHUNK=32
// rows staged bf16 in LDS per chunk. Pass 3: lane owns dims 2L,2L+1.
//   read_bf=0: pass1 reads fp32 x (exact e); write_bf -> emit bf16 x.
//   read_bf=1: pass1 reads bf16 xbf.
// ---------------------------------------------------------------------------
__global__ __launch_bounds__(128) void seg_attn_wave_k(
    const float* __restrict__ x, ushort_t* __restrict__ xbf,
    const int* __restrict__ seg, const float* __restrict__ hbuf,
    float* __restrict__ qstar, __hip_bfloat16* __restrict__ abuf,
    int read_bf, int write_bf)
{
    const int tid  = threadIdx.x;
    const int wv   = tid >> 6, lane = tid & 63;
    const int b    = blockIdx.x * 2 + wv;
    const int l16  = lane & 15, grp = lane >> 4;   // 4 row-groups of 16 lanes

    __shared__ ushort_t xs[2][WCHUNK * 128];   // 8 KB per wave
    __shared__ float    es[2][WCHUNK];
    ushort_t* xw = xs[wv];
    float*    ew = es[wv];

    const int ns = seg[b], ne = seg[b + 1];

    const float4* hp = (const float4*)(hbuf + (size_t)b * DIM);
    float4 h0, h1, hA, hB;
    if (read_bf) { hA = hp[2 * l16]; hB = hp[2 * l16 + 1]; }   // dims [8l16,+8)
    else         { h0 = hp[l16];     h1 = hp[l16 + 16];    }   // dims [4l16,+4),[64+4l16,+4)

    float m = -INFINITY, den = 0.f, r0 = 0.f, r1 = 0.f;
    const int d0 = 2 * lane;   // dims owned by this lane

    for (int c0 = ns; c0 < ne; c0 += WCHUNK) {
        const int cc = min(WCHUNK, ne - c0);

        LGKM_WAIT();   // prior chunk's LDS reads drained before overwrite
        // ---- pass 1: e + bf16 staging; 4 rows in flight (one per group)
        if (read_bf) {
            for (int j = c0 + grp; j < c0 + cc; j += 4) {
                const int row = j - c0;
                int4 v = *(const int4*)(xbf + (size_t)j * 128 + 8 * l16);
                *(int4*)(&xw[row * 128 + 8 * l16]) = v;
                const ushort_t* u = (const ushort_t*)&v;
                float s = bfu2f(u[0])*hA.x + bfu2f(u[1])*hA.y
                        + bfu2f(u[2])*hA.z + bfu2f(u[3])*hA.w
                        + bfu2f(u[4])*hB.x + bfu2f(u[5])*hB.y
                        + bfu2f(u[6])*hB.z + bfu2f(u[7])*hB.w;
                s += __shfl_xor(s, 1);
                s += __shfl_xor(s, 2);
                s += __shfl_xor(s, 4);
                s += __shfl_xor(s, 8);
                if (l16 == 0) ew[row] = s;
            }
        } else {
            for (int j = c0 + grp; j < c0 + cc; j += 4) {
                const int row = j - c0;
                const float4* xp = (const float4*)(x + (size_t)j * DIM);
                float4 xa = xp[l16], xb = xp[l16 + 16];
                float s = xa.x*h0.x + xa.y*h0.y + xa.z*h0.z + xa.w*h0.w
                        + xb.x*h1.x + xb.y*h1.y + xb.z*h1.z + xb.w*h1.w;
                s += __shfl_xor(s, 1);
                s += __shfl_xor(s, 2);
                s += __shfl_xor(s, 4);
                s += __shfl_xor(s, 8);
                uint2 pa, pb;
                pa.x = (unsigned)f2bf_u(xa.x) | ((unsigned)f2bf_u(xa.y) << 16);
                pa.y = (unsigned)f2bf_u(xa.z) | ((unsigned)f2bf_u(xa.w) << 16);
                pb.x = (unsigned)f2bf_u(xb.x) | ((unsigned)f2bf_u(xb.y) << 16);
                pb.y = (unsigned)f2bf_u(xb.z) | ((unsigned)f2bf_u(xb.w) << 16);
                *(uint2*)(&xw[row * 128 + 4 * l16])      = pa;
                *(uint2*)(&xw[row * 128 + 64 + 4 * l16]) = pb;
                if (write_bf) {
                    *(uint2*)(xbf + (size_t)j * 128 + 4 * l16)      = pa;
                    *(uint2*)(xbf + (size_t)j * 128 + 64 + 4 * l16) = pb;
                }
                if (l16 == 0) ew[row] = s;
            }
        }
        LGKM_WAIT();   // es/xs writes visible to whole wave

        // ---- chunk max (64-lane shfl reduce; lanes 32-63 mirror 0-31)
        const int idx = lane & 31;
        float cm = (idx < cc) ? ew[idx] : -INFINITY;
        #pragma unroll
        for (int o = 1; o < 64; o <<= 1) cm = fmaxf(cm, __shfl_xor(cm, o));

        const float mn = fmaxf(m, cm);
        const float scale = expf(m - mn);   // first chunk: exp(-inf)=0

        // ---- exp in place (lanes 0-31) + denom reduce
        float w = 0.f;
        if (lane < 32 && lane < cc) {
            w = expf(ew[lane] - mn);
            ew[lane] = w;
        }
        float cd = w;
        #pragma unroll
        for (int o = 1; o < 64; o <<= 1) cd += __shfl_xor(cd, o);
        LGKM_WAIT();   // exp'd es visible before pass 3 reads

        den = den * scale + cd;
        r0 *= scale;
        r1 *= scale;

        // ---- pass 3: weighted sum from LDS; lane owns dims d0, d0+1
        #pragma unroll 4
        for (int row = 0; row < cc; ++row) {
            float wr = ew[row];   // broadcast read
            unsigned p = *(const unsigned*)(&xw[row * 128 + d0]);
            r0 = fmaf(wr, bfu2f((ushort_t)(p & 0xffff)), r0);
            r1 = fmaf(wr, bfu2f((ushort_t)(p >> 16)), r1);
        }

        m = mn;
    }

    const float rden = 1.f / (den + 1e-16f);
    const float rv0 = r0 * rden, rv1 = r1 * rden;
    *(float2*)(qstar + (size_t)b * 256 + DIM + d0) = make_float2(rv0, rv1);
    unsigned pk = (unsigned)f2bf_u(rv0) | ((unsigned)f2bf_u(rv1) << 16);
    *(unsigned*)(abuf + (size_t)b * 384 + 128 + d0) = pk;
}

// ---------------------------------------------------------------------------
extern "C" void kernel_launch(void* const* d_in, const int* in_sizes, int n_in,
                              void* d_out, int out_size, void* d_ws, size_t ws_size,
                              hipStream_t stream) {
    const float* x     = (const float*)d_in[0];
    const int*   batch = (const int*)d_in[1];
    const float* Wih   = (const float*)d_in[2];
    const float* Whh   = (const float*)d_in[3];
    const float* bih   = (const float*)d_in[4];
    const float* bhh   = (const float*)d_in[5];
    float* out = (float*)d_out;

    // workspace layout
    float* hbuf  = (float*)d_ws;                            // 8192*128 f32
    float* cbuf  = hbuf  + (size_t)NSEG * DIM;
    float* gates = cbuf  + (size_t)NSEG * DIM;              // 8192*512 f32
    __hip_bfloat16* abuf = (__hip_bfloat16*)(gates + (size_t)NSEG * 512);  // 8192*384
    __hip_bfloat16* wbuf = abuf + (size_t)NSEG * 384;       // 512*384
    int* seg = (int*)(wbuf + (size_t)512 * 384);
    // xbf after seg, 16-B aligned
    size_t fixed_bytes = (size_t)((char*)(seg + NSEG + 1) - (char*)d_ws);
    size_t xbf_off = (fixed_bytes + 15) & ~(size_t)15;
    ushort_t* xbf = (ushort_t*)((char*)d_ws + xbf_off);
    size_t need = xbf_off + (size_t)NNODES * DIM * sizeof(ushort_t);
    const int use_xbf = (ws_size >= need) ? 1 : 0;

    hipMemsetAsync(hbuf, 0, (size_t)NSEG * DIM * sizeof(float), stream);
    hipMemsetAsync(cbuf, 0, (size_t)NSEG * DIM * sizeof(float), stream);
    hipMemsetAsync(abuf, 0, (size_t)NSEG * 384 * sizeof(__hip_bfloat16), stream);
    hipMemsetAsync(out,  0, (size_t)NSEG * 2 * DIM * sizeof(float), stream);

    seg_bounds_k<<<(NSEG + 256) / 256, 256, 0, stream>>>(batch, seg, NNODES);
    wconv_k<<<(512 * 384) / 256, 256, 0, stream>>>(Wih, Whh, wbuf);

    dim3 ggrid(512 / 64, NSEG / 128);   // (8, 64)
    for (int t = 0; t < TSTEPS; ++t) {
        gemm_mfma_k<<<ggrid, 256, 0, stream>>>(abuf, wbuf, gates);
        lstm_cell_k<<<(NSEG * DIM) / 256, 256, 0, stream>>>(gates, bih, bhh, cbuf, hbuf, out, abuf);
        const int read_bf  = (use_xbf && t > 0) ? 1 : 0;
        const int write_bf = (use_xbf && t == 0) ? 1 : 0;
        seg_attn_wave_k<<<NSEG / 2, 128, 0, stream>>>(x, xbf, seg, hbuf, out, abuf,
                                                      read_bf, write_bf);
    }
}

// Round 9
// 489.967 us; speedup vs baseline: 1.7366x; 1.0010x over previous
//
#include <hip/hip_runtime.h>
#include <hip/hip_bf16.h>
#include <cstddef>
#include <cstdint>

#define NNODES 500000
#define DIM    128
#define NSEG   8192
#define TSTEPS 6
#define WCHUNK 32      // rows staged per wave-chunk

typedef __attribute__((ext_vector_type(8))) short bf16x8;
typedef __attribute__((ext_vector_type(4))) float f32x4;
typedef unsigned short ushort_t;

static __device__ inline ushort_t f2bf_u(float f) {
    __hip_bfloat16 h = __float2bfloat16(f);
    return *reinterpret_cast<ushort_t*>(&h);
}
static __device__ inline float bfu2f(ushort_t u) {
    union { unsigned i; float f; } c; c.i = ((unsigned)u) << 16; return c.f;
}
#define LGKM_WAIT() __asm__ __volatile__("s_waitcnt lgkmcnt(0)" ::: "memory")

// ---------------------------------------------------------------------------
// Segment bounds: batch is sorted; seg[b] = lower_bound(batch, b), seg[B] = N.
// ---------------------------------------------------------------------------
__global__ void seg_bounds_k(const int* __restrict__ batch, int* __restrict__ seg, int n) {
    int b = blockIdx.x * blockDim.x + threadIdx.x;
    if (b > NSEG) return;
    int lo = 0, hi = n;
    while (lo < hi) {
        int mid = (lo + hi) >> 1;
        if (batch[mid] < b) lo = mid + 1; else hi = mid;
    }
    seg[b] = lo;
}

// ---------------------------------------------------------------------------
// One-time: wbuf[n][k] bf16, k<256 from Wih[n][k], else Whh[n][k-256].
// ---------------------------------------------------------------------------
__global__ __launch_bounds__(256) void wconv_k(
    const float* __restrict__ Wih, const float* __restrict__ Whh,
    __hip_bfloat16* __restrict__ wbuf)
{
    int idx = blockIdx.x * 256 + threadIdx.x;    // 512*384 exact
    int n = idx / 384, k = idx - n * 384;
    float v = (k < 256) ? Wih[n * 256 + k] : Whh[n * 128 + (k - 256)];
    wbuf[idx] = __float2bfloat16(v);
}

// ---------------------------------------------------------------------------
// gates = Abf @ Wbf^T  (fp32 accumulate). A=[8192][384] bf16 = [q|r|h],
// W=[512][384] bf16. MFMA 16x16x32, BM=128 BN=64 BK=64, 4 waves (2x2).
// ---------------------------------------------------------------------------
__global__ __launch_bounds__(256) void gemm_mfma_k(
    const __hip_bfloat16* __restrict__ abuf,
    const __hip_bfloat16* __restrict__ wbuf,
    float* __restrict__ gates)
{
    __shared__ char As[128 * 128];
    __shared__ char Bs[64 * 128];
    const int tid  = threadIdx.x;
    const int lane = tid & 63, wave = tid >> 6;
    const int wrow = (wave >> 1) * 64;
    const int wcol = (wave & 1) * 32;
    const int m0 = blockIdx.y * 128;
    const int n0 = blockIdx.x * 64;

    const int ar  = tid >> 1;
    const int acb = (tid & 1) * 64;
    const int br  = tid >> 2;
    const int bcb = (tid & 3) * 32;

    const char* aP = (const char*)(abuf + (size_t)(m0 + ar) * 384) + acb;
    const char* bP = (const char*)(wbuf + (size_t)(n0 + br) * 384) + bcb;

    f32x4 acc[4][2] = {};

    int4 ra[4]; int4 rb2[2];
    #pragma unroll
    for (int c = 0; c < 4; ++c) ra[c]  = *(const int4*)(aP + c * 16);
    #pragma unroll
    for (int c = 0; c < 2; ++c) rb2[c] = *(const int4*)(bP + c * 16);

    char* asw = As + ar * 128;
    char* bsw = Bs + br * 128;
    const int amask = (ar & 7) << 4;
    const int bmask = (br & 7) << 4;

    for (int s = 0; s < 6; ++s) {
        __syncthreads();
        #pragma unroll
        for (int c = 0; c < 4; ++c)
            *(int4*)(asw + ((acb + c * 16) ^ amask)) = ra[c];
        #pragma unroll
        for (int c = 0; c < 2; ++c)
            *(int4*)(bsw + ((bcb + c * 16) ^ bmask)) = rb2[c];
        __syncthreads();

        if (s < 5) {
            const char* aN = aP + (size_t)(s + 1) * 128;
            const char* bN = bP + (size_t)(s + 1) * 128;
            #pragma unroll
            for (int c = 0; c < 4; ++c) ra[c]  = *(const int4*)(aN + c * 16);
            #pragma unroll
            for (int c = 0; c < 2; ++c) rb2[c] = *(const int4*)(bN + c * 16);
        }

        #pragma unroll
        for (int ks = 0; ks < 2; ++ks) {
            const int kb = ks * 64 + ((lane >> 4) << 4);
            bf16x8 af[4], bfr[2];
            #pragma unroll
            for (int rbk = 0; rbk < 4; ++rbk) {
                int r = wrow + rbk * 16 + (lane & 15);
                af[rbk] = *(const bf16x8*)(As + r * 128 + (kb ^ ((r & 7) << 4)));
            }
            #pragma unroll
            for (int cb = 0; cb < 2; ++cb) {
                int n = wcol + cb * 16 + (lane & 15);
                bfr[cb] = *(const bf16x8*)(Bs + n * 128 + (kb ^ ((n & 7) << 4)));
            }
            #pragma unroll
            for (int rbk = 0; rbk < 4; ++rbk)
                #pragma unroll
                for (int cb = 0; cb < 2; ++cb)
                    acc[rbk][cb] = __builtin_amdgcn_mfma_f32_16x16x32_bf16(
                        af[rbk], bfr[cb], acc[rbk][cb], 0, 0, 0);
        }
    }

    const int rowb = (lane >> 4) << 2;
    const int coll = lane & 15;
    #pragma unroll
    for (int rbk = 0; rbk < 4; ++rbk)
        #pragma unroll
        for (int cb = 0; cb < 2; ++cb) {
            int row = m0 + wrow + rbk * 16 + rowb;
            int col = n0 + wcol + cb * 16 + coll;
            float* gp = gates + (size_t)row * 512 + col;
            #pragma unroll
            for (int reg = 0; reg < 4; ++reg)
                gp[(size_t)reg * 512] = acc[rbk][cb][reg];
        }
}

// ---------------------------------------------------------------------------
// LSTM cell elementwise; writes q=h to d_out[:,0:128], h to abuf cols [0,128)
// and [256,384) (bf16), plus fp32 hbuf/cbuf.
// ---------------------------------------------------------------------------
__global__ __launch_bounds__(256) void lstm_cell_k(
    const float* __restrict__ gates, const float* __restrict__ bih,
    const float* __restrict__ bhh,   float* __restrict__ cbuf,
    float* __restrict__ hbuf,        float* __restrict__ qstar,
    __hip_bfloat16* __restrict__ abuf)
{
    int idx = blockIdx.x * 256 + threadIdx.x;   // b*128 + d
    int b = idx >> 7, d = idx & 127;
    const float* g = gates + (size_t)b * 512;
    float gi = g[d]       + bih[d]       + bhh[d];
    float gf = g[128 + d] + bih[128 + d] + bhh[128 + d];
    float gg = g[256 + d] + bih[256 + d] + bhh[256 + d];
    float go = g[384 + d] + bih[384 + d] + bhh[384 + d];
    float iv = 1.f / (1.f + expf(-gi));
    float fv = 1.f / (1.f + expf(-gf));
    float gv = tanhf(gg);
    float ov = 1.f / (1.f + expf(-go));
    float c  = fv * cbuf[idx] + iv * gv;
    float h  = ov * tanhf(c);
    cbuf[idx] = c;
    hbuf[idx] = h;
    qstar[(size_t)b * 256 + d] = h;
    __hip_bfloat16 hb = __float2bfloat16(h);
    abuf[(size_t)b * 384 + d] = hb;
    abuf[(size_t)b * 384 + 256 + d] = hb;
}

// ---------------------------------------------------------------------------
// 2-waves-per-segment fused attention. Block = one segment; wave wv handles
// chunks ns + (wv + 2k)*WCHUNK. Wave-synchronous inner loop (lgkmcnt fences,
// no __syncthreads); one barrier at the end to merge (m, den, r[128]).
// Pass1 fast path (full chunk) unrolls 2 rows/iter with loads issued early
// (MLP). Pass 3: lane owns dims 2*lane, 2*lane+1 from LDS bf16 staging.
// ---------------------------------------------------------------------------
__global__ __launch_bounds__(128) void seg_attn_wave2_k(
    const float* __restrict__ x, ushort_t* __restrict__ xbf,
    const int* __restrict__ seg, const float* __restrict__ hbuf,
    float* __restrict__ qstar, __hip_bfloat16* __restrict__ abuf,
    int read_bf, int write_bf)
{
    const int tid  = threadIdx.x;
    const int wv   = tid >> 6, lane = tid & 63;
    const int b    = blockIdx.x;
    const int l16  = lane & 15, grp = lane >> 4;   // 4 row-groups of 16 lanes

    __shared__ ushort_t xs[2][WCHUNK * 128];   // 8 KB per wave
    __shared__ float    es[2][WCHUNK];
    __shared__ float    mstat[2][2];
    __shared__ float    rbuf[2][128];

    const int ns = seg[b], ne = seg[b + 1];
    if (ns >= ne) {   // empty segment: r = 0 (block-uniform branch)
        if (tid < 128) {
            qstar[(size_t)b * 256 + DIM + tid] = 0.f;
            abuf[(size_t)b * 384 + 128 + tid] = __float2bfloat16(0.f);
        }
        return;
    }

    ushort_t* xw = xs[wv];
    float*    ew = es[wv];

    const float4* hp = (const float4*)(hbuf + (size_t)b * DIM);
    float4 h0, h1, hA, hB;
    if (read_bf) { hA = hp[2 * l16]; hB = hp[2 * l16 + 1]; }   // dims [8l16,+8)
    else         { h0 = hp[l16];     h1 = hp[l16 + 16];    }

    float m = -INFINITY, den = 0.f, r0 = 0.f, r1 = 0.f;
    const int d0 = 2 * lane;

    for (int c0 = ns + wv * WCHUNK; c0 < ne; c0 += 2 * WCHUNK) {
        const int cc = min(WCHUNK, ne - c0);

        LGKM_WAIT();   // prior chunk's LDS reads drained before overwrite
        // ---- pass 1: e + bf16 staging
        if (read_bf) {
            if (cc == WCHUNK) {
                #pragma unroll
                for (int it = 0; it < WCHUNK / 8; ++it) {
                    const int raw = grp + it * 8, rbw = raw + 4;
                    int4 v0 = *(const int4*)(xbf + (size_t)(c0 + raw) * 128 + 8 * l16);
                    int4 v1 = *(const int4*)(xbf + (size_t)(c0 + rbw) * 128 + 8 * l16);
                    {
                        *(int4*)(&xw[raw * 128 + 8 * l16]) = v0;
                        const ushort_t* u = (const ushort_t*)&v0;
                        float s = bfu2f(u[0])*hA.x + bfu2f(u[1])*hA.y
                                + bfu2f(u[2])*hA.z + bfu2f(u[3])*hA.w
                                + bfu2f(u[4])*hB.x + bfu2f(u[5])*hB.y
                                + bfu2f(u[6])*hB.z + bfu2f(u[7])*hB.w;
                        s += __shfl_xor(s, 1); s += __shfl_xor(s, 2);
                        s += __shfl_xor(s, 4); s += __shfl_xor(s, 8);
                        if (l16 == 0) ew[raw] = s;
                    }
                    {
                        *(int4*)(&xw[rbw * 128 + 8 * l16]) = v1;
                        const ushort_t* u = (const ushort_t*)&v1;
                        float s = bfu2f(u[0])*hA.x + bfu2f(u[1])*hA.y
                                + bfu2f(u[2])*hA.z + bfu2f(u[3])*hA.w
                                + bfu2f(u[4])*hB.x + bfu2f(u[5])*hB.y
                                + bfu2f(u[6])*hB.z + bfu2f(u[7])*hB.w;
                        s += __shfl_xor(s, 1); s += __shfl_xor(s, 2);
                        s += __shfl_xor(s, 4); s += __shfl_xor(s, 8);
                        if (l16 == 0) ew[rbw] = s;
                    }
                }
            } else {
                for (int j = c0 + grp; j < c0 + cc; j += 4) {
                    const int row = j - c0;
                    int4 v = *(const int4*)(xbf + (size_t)j * 128 + 8 * l16);
                    *(int4*)(&xw[row * 128 + 8 * l16]) = v;
                    const ushort_t* u = (const ushort_t*)&v;
                    float s = bfu2f(u[0])*hA.x + bfu2f(u[1])*hA.y
                            + bfu2f(u[2])*hA.z + bfu2f(u[3])*hA.w
                            + bfu2f(u[4])*hB.x + bfu2f(u[5])*hB.y
                            + bfu2f(u[6])*hB.z + bfu2f(u[7])*hB.w;
                    s += __shfl_xor(s, 1); s += __shfl_xor(s, 2);
                    s += __shfl_xor(s, 4); s += __shfl_xor(s, 8);
                    if (l16 == 0) ew[row] = s;
                }
            }
        } else {
            if (cc == WCHUNK) {
                #pragma unroll
                for (int it = 0; it < WCHUNK / 8; ++it) {
                    const int raw = grp + it * 8, rbw = raw + 4;
                    const float4* xp0 = (const float4*)(x + (size_t)(c0 + raw) * DIM);
                    const float4* xp1 = (const float4*)(x + (size_t)(c0 + rbw) * DIM);
                    float4 xa0 = xp0[l16], xb0 = xp0[l16 + 16];
                    float4 xa1 = xp1[l16], xb1 = xp1[l16 + 16];
                    {
                        float s = xa0.x*h0.x + xa0.y*h0.y + xa0.z*h0.z + xa0.w*h0.w
                                + xb0.x*h1.x + xb0.y*h1.y + xb0.z*h1.z + xb0.w*h1.w;
                        s += __shfl_xor(s, 1); s += __shfl_xor(s, 2);
                        s += __shfl_xor(s, 4); s += __shfl_xor(s, 8);
                        uint2 pa, pb;
                        pa.x = (unsigned)f2bf_u(xa0.x) | ((unsigned)f2bf_u(xa0.y) << 16);
                        pa.y = (unsigned)f2bf_u(xa0.z) | ((unsigned)f2bf_u(xa0.w) << 16);
                        pb.x = (unsigned)f2bf_u(xb0.x) | ((unsigned)f2bf_u(xb0.y) << 16);
                        pb.y = (unsigned)f2bf_u(xb0.z) | ((unsigned)f2bf_u(xb0.w) << 16);
                        *(uint2*)(&xw[raw * 128 + 4 * l16])      = pa;
                        *(uint2*)(&xw[raw * 128 + 64 + 4 * l16]) = pb;
                        if (write_bf) {
                            *(uint2*)(xbf + (size_t)(c0 + raw) * 128 + 4 * l16)      = pa;
                            *(uint2*)(xbf + (size_t)(c0 + raw) * 128 + 64 + 4 * l16) = pb;
                        }
                        if (l16 == 0) ew[raw] = s;
                    }
                    {
                        float s = xa1.x*h0.x + xa1.y*h0.y + xa1.z*h0.z + xa1.w*h0.w
                                + xb1.x*h1.x + xb1.y*h1.y + xb1.z*h1.z + xb1.w*h1.w;
                        s += __shfl_xor(s, 1); s += __shfl_xor(s, 2);
                        s += __shfl_xor(s, 4); s += __shfl_xor(s, 8);
                        uint2 pa, pb;
                        pa.x = (unsigned)f2bf_u(xa1.x) | ((unsigned)f2bf_u(xa1.y) << 16);
                        pa.y = (unsigned)f2bf_u(xa1.z) | ((unsigned)f2bf_u(xa1.w) << 16);
                        pb.x = (unsigned)f2bf_u(xb1.x) | ((unsigned)f2bf_u(xb1.y) << 16);
                        pb.y = (unsigned)f2bf_u(xb1.z) | ((unsigned)f2bf_u(xb1.w) << 16);
                        *(uint2*)(&xw[rbw * 128 + 4 * l16])      = pa;
                        *(uint2*)(&xw[rbw * 128 + 64 + 4 * l16]) = pb;
                        if (write_bf) {
                            *(uint2*)(xbf + (size_t)(c0 + rbw) * 128 + 4 * l16)      = pa;
                            *(uint2*)(xbf + (size_t)(c0 + rbw) * 128 + 64 + 4 * l16) = pb;
                        }
                        if (l16 == 0) ew[rbw] = s;
                    }
                }
            } else {
                for (int j = c0 + grp; j < c0 + cc; j += 4) {
                    const int row = j - c0;
                    const float4* xp = (const float4*)(x + (size_t)j * DIM);
                    float4 xa = xp[l16], xb = xp[l16 + 16];
                    float s = xa.x*h0.x + xa.y*h0.y + xa.z*h0.z + xa.w*h0.w
                            + xb.x*h1.x + xb.y*h1.y + xb.z*h1.z + xb.w*h1.w;
                    s += __shfl_xor(s, 1); s += __shfl_xor(s, 2);
                    s += __shfl_xor(s, 4); s += __shfl_xor(s, 8);
                    uint2 pa, pb;
                    pa.x = (unsigned)f2bf_u(xa.x) | ((unsigned)f2bf_u(xa.y) << 16);
                    pa.y = (unsigned)f2bf_u(xa.z) | ((unsigned)f2bf_u(xa.w) << 16);
                    pb.x = (unsigned)f2bf_u(xb.x) | ((unsigned)f2bf_u(xb.y) << 16);
                    pb.y = (unsigned)f2bf_u(xb.z) | ((unsigned)f2bf_u(xb.w) << 16);
                    *(uint2*)(&xw[row * 128 + 4 * l16])      = pa;
                    *(uint2*)(&xw[row * 128 + 64 + 4 * l16]) = pb;
                    if (write_bf) {
                        *(uint2*)(xbf + (size_t)j * 128 + 4 * l16)      = pa;
                        *(uint2*)(xbf + (size_t)j * 128 + 64 + 4 * l16) = pb;
                    }
                    if (l16 == 0) ew[row] = s;
                }
            }
        }
        LGKM_WAIT();   // es/xs writes visible to whole wave

        // ---- chunk max (64-lane shfl reduce; lanes 32-63 mirror 0-31)
        const int idx = lane & 31;
        float cm = (idx < cc) ? ew[idx] : -INFINITY;
        #pragma unroll
        for (int o = 1; o < 64; o <<= 1) cm = fmaxf(cm, __shfl_xor(cm, o));

        const float mn = fmaxf(m, cm);
        const float scale = expf(m - mn);   // first chunk: exp(-inf)=0

        // ---- exp in place (lanes 0-31) + denom reduce
        float w = 0.f;
        if (lane < 32 && lane < cc) {
            w = expf(ew[lane] - mn);
            ew[lane] = w;
        }
        float cd = w;
        #pragma unroll
        for (int o = 1; o < 64; o <<= 1) cd += __shfl_xor(cd, o);
        LGKM_WAIT();   // exp'd es visible before pass 3 reads

        den = den * scale + cd;
        r0 *= scale;
        r1 *= scale;

        // ---- pass 3: weighted sum from LDS; lane owns dims d0, d0+1
        #pragma unroll 4
        for (int row = 0; row < cc; ++row) {
            float wr = ew[row];   // broadcast read
            unsigned p = *(const unsigned*)(&xw[row * 128 + d0]);
            r0 = fmaf(wr, bfu2f((ushort_t)(p & 0xffff)), r0);
            r1 = fmaf(wr, bfu2f((ushort_t)(p >> 16)), r1);
        }

        m = mn;
    }

    // ---- cross-wave merge (one barrier)
    if (lane == 0) { mstat[wv][0] = m; mstat[wv][1] = den; }
    rbuf[wv][d0]     = r0;
    rbuf[wv][d0 + 1] = r1;
    __syncthreads();

    {
        const float m0s = mstat[0][0], m1s = mstat[1][0];
        const float dn0 = mstat[0][1], dn1 = mstat[1][1];
        const float ms  = fmaxf(m0s, m1s);   // wave0 always has a chunk -> finite
        const float k0  = expf(m0s - ms);
        const float k1  = expf(m1s - ms);    // m1s=-inf (no chunks) -> 0
        const float dtot = k0 * dn0 + k1 * dn1;
        const float rv = (k0 * rbuf[0][tid] + k1 * rbuf[1][tid]) / (dtot + 1e-16f);
        qstar[(size_t)b * 256 + DIM + tid] = rv;
        abuf[(size_t)b * 384 + 128 + tid] = __float2bfloat16(rv);
    }
}

// ---------------------------------------------------------------------------
extern "C" void kernel_launch(void* const* d_in, const int* in_sizes, int n_in,
                              void* d_out, int out_size, void* d_ws, size_t ws_size,
                              hipStream_t stream) {
    const float* x     = (const float*)d_in[0];
    const int*   batch = (const int*)d_in[1];
    const float* Wih   = (const float*)d_in[2];
    const float* Whh   = (const float*)d_in[3];
    const float* bih   = (const float*)d_in[4];
    const float* bhh   = (const float*)d_in[5];
    float* out = (float*)d_out;

    // workspace layout
    float* hbuf  = (float*)d_ws;                            // 8192*128 f32
    float* cbuf  = hbuf  + (size_t)NSEG * DIM;
    float* gates = cbuf  + (size_t)NSEG * DIM;              // 8192*512 f32
    __hip_bfloat16* abuf = (__hip_bfloat16*)(gates + (size_t)NSEG * 512);  // 8192*384
    __hip_bfloat16* wbuf = abuf + (size_t)NSEG * 384;       // 512*384
    int* seg = (int*)(wbuf + (size_t)512 * 384);
    // xbf after seg, 16-B aligned
    size_t fixed_bytes = (size_t)((char*)(seg + NSEG + 1) - (char*)d_ws);
    size_t xbf_off = (fixed_bytes + 15) & ~(size_t)15;
    ushort_t* xbf = (ushort_t*)((char*)d_ws + xbf_off);
    size_t need = xbf_off + (size_t)NNODES * DIM * sizeof(ushort_t);
    const int use_xbf = (ws_size >= need) ? 1 : 0;

    hipMemsetAsync(hbuf, 0, (size_t)NSEG * DIM * sizeof(float), stream);
    hipMemsetAsync(cbuf, 0, (size_t)NSEG * DIM * sizeof(float), stream);
    hipMemsetAsync(abuf, 0, (size_t)NSEG * 384 * sizeof(__hip_bfloat16), stream);
    hipMemsetAsync(out,  0, (size_t)NSEG * 2 * DIM * sizeof(float), stream);

    seg_bounds_k<<<(NSEG + 256) / 256, 256, 0, stream>>>(batch, seg, NNODES);
    wconv_k<<<(512 * 384) / 256, 256, 0, stream>>>(Wih, Whh, wbuf);

    dim3 ggrid(512 / 64, NSEG / 128);   // (8, 64)
    for (int t = 0; t < TSTEPS; ++t) {
        gemm_mfma_k<<<ggrid, 256, 0, stream>>>(abuf, wbuf, gates);
        lstm_cell_k<<<(NSEG * DIM) / 256, 256, 0, stream>>>(gates, bih, bhh, cbuf, hbuf, out, abuf);
        const int read_bf  = (use_xbf && t > 0) ? 1 : 0;
        const int write_bf = (use_xbf && t == 0) ? 1 : 0;
        seg_attn_wave2_k<<<NSEG, 128, 0, stream>>>(x, xbf, seg, hbuf, out, abuf,
                                                   read_bf, write_bf);
    }
}

// Round 10
// 431.273 us; speedup vs baseline: 1.9730x; 1.1361x over previous
//
#include <hip/hip_runtime.h>
#include <hip/hip_bf16.h>
#include <cstddef>
#include <cstdint>

#define NNODES 500000
#define DIM    128
#define NSEG   8192
#define TSTEPS 6
#define WCHUNK 32      // rows staged per wave-chunk

typedef __attribute__((ext_vector_type(8))) short bf16x8;
typedef __attribute__((ext_vector_type(4))) float f32x4;
typedef unsigned short ushort_t;

static __device__ inline ushort_t f2bf_u(float f) {
    __hip_bfloat16 h = __float2bfloat16(f);
    return *reinterpret_cast<ushort_t*>(&h);
}
static __device__ inline float bfu2f(ushort_t u) {
    union { unsigned i; float f; } c; c.i = ((unsigned)u) << 16; return c.f;
}
#define LGKM_WAIT() __asm__ __volatile__("s_waitcnt lgkmcnt(0)" ::: "memory")

// ---------------------------------------------------------------------------
// Segment bounds: batch is sorted; seg[b] = lower_bound(batch, b), seg[B] = N.
// ---------------------------------------------------------------------------
__global__ void seg_bounds_k(const int* __restrict__ batch, int* __restrict__ seg, int n) {
    int b = blockIdx.x * blockDim.x + threadIdx.x;
    if (b > NSEG) return;
    int lo = 0, hi = n;
    while (lo < hi) {
        int mid = (lo + hi) >> 1;
        if (batch[mid] < b) lo = mid + 1; else hi = mid;
    }
    seg[b] = lo;
}

// ---------------------------------------------------------------------------
// One-time: wbuf[n][k] bf16, k<256 from Wih[n][k], else Whh[n][k-256].
// ---------------------------------------------------------------------------
__global__ __launch_bounds__(256) void wconv_k(
    const float* __restrict__ Wih, const float* __restrict__ Whh,
    __hip_bfloat16* __restrict__ wbuf)
{
    int idx = blockIdx.x * 256 + threadIdx.x;    // 512*384 exact
    int n = idx / 384, k = idx - n * 384;
    float v = (k < 256) ? Wih[n * 256 + k] : Whh[n * 128 + (k - 256)];
    wbuf[idx] = __float2bfloat16(v);
}

// ---------------------------------------------------------------------------
// gates = Abf @ Wbf^T  (fp32 accumulate). A=[8192][384] bf16 = [q|r|h],
// W=[512][384] bf16. MFMA 16x16x32, BM=128 BN=64 BK=64, 4 waves (2x2).
// ---------------------------------------------------------------------------
__global__ __launch_bounds__(256) void gemm_mfma_k(
    const __hip_bfloat16* __restrict__ abuf,
    const __hip_bfloat16* __restrict__ wbuf,
    float* __restrict__ gates)
{
    __shared__ char As[128 * 128];
    __shared__ char Bs[64 * 128];
    const int tid  = threadIdx.x;
    const int lane = tid & 63, wave = tid >> 6;
    const int wrow = (wave >> 1) * 64;
    const int wcol = (wave & 1) * 32;
    const int m0 = blockIdx.y * 128;
    const int n0 = blockIdx.x * 64;

    const int ar  = tid >> 1;
    const int acb = (tid & 1) * 64;
    const int br  = tid >> 2;
    const int bcb = (tid & 3) * 32;

    const char* aP = (const char*)(abuf + (size_t)(m0 + ar) * 384) + acb;
    const char* bP = (const char*)(wbuf + (size_t)(n0 + br) * 384) + bcb;

    f32x4 acc[4][2] = {};

    int4 ra[4]; int4 rb2[2];
    #pragma unroll
    for (int c = 0; c < 4; ++c) ra[c]  = *(const int4*)(aP + c * 16);
    #pragma unroll
    for (int c = 0; c < 2; ++c) rb2[c] = *(const int4*)(bP + c * 16);

    char* asw = As + ar * 128;
    char* bsw = Bs + br * 128;
    const int amask = (ar & 7) << 4;
    const int bmask = (br & 7) << 4;

    for (int s = 0; s < 6; ++s) {
        __syncthreads();
        #pragma unroll
        for (int c = 0; c < 4; ++c)
            *(int4*)(asw + ((acb + c * 16) ^ amask)) = ra[c];
        #pragma unroll
        for (int c = 0; c < 2; ++c)
            *(int4*)(bsw + ((bcb + c * 16) ^ bmask)) = rb2[c];
        __syncthreads();

        if (s < 5) {
            const char* aN = aP + (size_t)(s + 1) * 128;
            const char* bN = bP + (size_t)(s + 1) * 128;
            #pragma unroll
            for (int c = 0; c < 4; ++c) ra[c]  = *(const int4*)(aN + c * 16);
            #pragma unroll
            for (int c = 0; c < 2; ++c) rb2[c] = *(const int4*)(bN + c * 16);
        }

        #pragma unroll
        for (int ks = 0; ks < 2; ++ks) {
            const int kb = ks * 64 + ((lane >> 4) << 4);
            bf16x8 af[4], bfr[2];
            #pragma unroll
            for (int rbk = 0; rbk < 4; ++rbk) {
                int r = wrow + rbk * 16 + (lane & 15);
                af[rbk] = *(const bf16x8*)(As + r * 128 + (kb ^ ((r & 7) << 4)));
            }
            #pragma unroll
            for (int cb = 0; cb < 2; ++cb) {
                int n = wcol + cb * 16 + (lane & 15);
                bfr[cb] = *(const bf16x8*)(Bs + n * 128 + (kb ^ ((n & 7) << 4)));
            }
            #pragma unroll
            for (int rbk = 0; rbk < 4; ++rbk)
                #pragma unroll
                for (int cb = 0; cb < 2; ++cb)
                    acc[rbk][cb] = __builtin_amdgcn_mfma_f32_16x16x32_bf16(
                        af[rbk], bfr[cb], acc[rbk][cb], 0, 0, 0);
        }
    }

    const int rowb = (lane >> 4) << 2;
    const int coll = lane & 15;
    #pragma unroll
    for (int rbk = 0; rbk < 4; ++rbk)
        #pragma unroll
        for (int cb = 0; cb < 2; ++cb) {
            int row = m0 + wrow + rbk * 16 + rowb;
            int col = n0 + wcol + cb * 16 + coll;
            float* gp = gates + (size_t)row * 512 + col;
            #pragma unroll
            for (int reg = 0; reg < 4; ++reg)
                gp[(size_t)reg * 512] = acc[rbk][cb][reg];
        }
}

// ---------------------------------------------------------------------------
// Fused LSTM + attention. Block = segment b (128 threads, 2 waves).
// Prologue: thread tid computes LSTM cell for dim tid (gates from GEMM, or
// bias-only at t0), updates cbuf, writes q=h to out/abuf, shares h via LDS.
// Then 2-waves-per-segment online-softmax attention (round-9 structure).
//   read_bf=0: pass1 reads fp32 x (exact e); write_bf -> emit bf16 x.
//   read_bf=1: pass1 reads bf16 xbf.
// ---------------------------------------------------------------------------
__global__ __launch_bounds__(128) void attn_lstm_k(
    const float* __restrict__ x, ushort_t* __restrict__ xbf,
    const int* __restrict__ seg, const float* __restrict__ gates,
    const float* __restrict__ bih, const float* __restrict__ bhh,
    float* __restrict__ cbuf, float* __restrict__ qstar,
    __hip_bfloat16* __restrict__ abuf,
    int t0, int read_bf, int write_bf)
{
    const int tid  = threadIdx.x;
    const int wv   = tid >> 6, lane = tid & 63;
    const int b    = blockIdx.x;
    const int l16  = lane & 15, grp = lane >> 4;   // 4 row-groups of 16 lanes

    __shared__ ushort_t xs[2][WCHUNK * 128];   // 8 KB per wave
    __shared__ float    es[2][WCHUNK];
    __shared__ float    mstat[2][2];
    __shared__ float    rbuf[2][128];
    __shared__ float    hsh[128];

    // ---- LSTM prologue: dim d = tid
    {
        const int d = tid;
        float gi, gf, gg, go;
        if (t0) {
            gi = bih[d]       + bhh[d];
            gf = bih[128 + d] + bhh[128 + d];
            gg = bih[256 + d] + bhh[256 + d];
            go = bih[384 + d] + bhh[384 + d];
        } else {
            const float* g = gates + (size_t)b * 512;
            gi = g[d]       + bih[d]       + bhh[d];
            gf = g[128 + d] + bih[128 + d] + bhh[128 + d];
            gg = g[256 + d] + bih[256 + d] + bhh[256 + d];
            go = g[384 + d] + bih[384 + d] + bhh[384 + d];
        }
        float iv = 1.f / (1.f + expf(-gi));
        float fv = 1.f / (1.f + expf(-gf));
        float gv = tanhf(gg);
        float ov = 1.f / (1.f + expf(-go));
        float cp = t0 ? 0.f : cbuf[(size_t)b * 128 + d];
        float c  = fv * cp + iv * gv;
        float h  = ov * tanhf(c);
        cbuf[(size_t)b * 128 + d] = c;
        qstar[(size_t)b * 256 + d] = h;
        __hip_bfloat16 hb = __float2bfloat16(h);
        abuf[(size_t)b * 384 + d] = hb;
        abuf[(size_t)b * 384 + 256 + d] = hb;
        hsh[d] = h;
    }
    __syncthreads();

    const int ns = seg[b], ne = seg[b + 1];
    if (ns >= ne) {   // empty segment: r = 0 (uniform branch)
        qstar[(size_t)b * 256 + DIM + tid] = 0.f;
        abuf[(size_t)b * 384 + 128 + tid] = __float2bfloat16(0.f);
        return;
    }

    ushort_t* xw = xs[wv];
    float*    ew = es[wv];

    float4 h0, h1, hA, hB;
    if (read_bf) {
        hA = *(const float4*)&hsh[8 * l16];
        hB = *(const float4*)&hsh[8 * l16 + 4];
    } else {
        h0 = *(const float4*)&hsh[4 * l16];
        h1 = *(const float4*)&hsh[64 + 4 * l16];
    }

    float m = -INFINITY, den = 0.f, r0 = 0.f, r1 = 0.f;
    const int d0 = 2 * lane;

    for (int c0 = ns + wv * WCHUNK; c0 < ne; c0 += 2 * WCHUNK) {
        const int cc = min(WCHUNK, ne - c0);

        LGKM_WAIT();   // prior chunk's LDS reads drained before overwrite
        // ---- pass 1: e + bf16 staging
        if (read_bf) {
            if (cc == WCHUNK) {
                #pragma unroll
                for (int it = 0; it < WCHUNK / 8; ++it) {
                    const int raw = grp + it * 8, rbw = raw + 4;
                    int4 v0 = *(const int4*)(xbf + (size_t)(c0 + raw) * 128 + 8 * l16);
                    int4 v1 = *(const int4*)(xbf + (size_t)(c0 + rbw) * 128 + 8 * l16);
                    {
                        *(int4*)(&xw[raw * 128 + 8 * l16]) = v0;
                        const ushort_t* u = (const ushort_t*)&v0;
                        float s = bfu2f(u[0])*hA.x + bfu2f(u[1])*hA.y
                                + bfu2f(u[2])*hA.z + bfu2f(u[3])*hA.w
                                + bfu2f(u[4])*hB.x + bfu2f(u[5])*hB.y
                                + bfu2f(u[6])*hB.z + bfu2f(u[7])*hB.w;
                        s += __shfl_xor(s, 1); s += __shfl_xor(s, 2);
                        s += __shfl_xor(s, 4); s += __shfl_xor(s, 8);
                        if (l16 == 0) ew[raw] = s;
                    }
                    {
                        *(int4*)(&xw[rbw * 128 + 8 * l16]) = v1;
                        const ushort_t* u = (const ushort_t*)&v1;
                        float s = bfu2f(u[0])*hA.x + bfu2f(u[1])*hA.y
                                + bfu2f(u[2])*hA.z + bfu2f(u[3])*hA.w
                                + bfu2f(u[4])*hB.x + bfu2f(u[5])*hB.y
                                + bfu2f(u[6])*hB.z + bfu2f(u[7])*hB.w;
                        s += __shfl_xor(s, 1); s += __shfl_xor(s, 2);
                        s += __shfl_xor(s, 4); s += __shfl_xor(s, 8);
                        if (l16 == 0) ew[rbw] = s;
                    }
                }
            } else {
                for (int j = c0 + grp; j < c0 + cc; j += 4) {
                    const int row = j - c0;
                    int4 v = *(const int4*)(xbf + (size_t)j * 128 + 8 * l16);
                    *(int4*)(&xw[row * 128 + 8 * l16]) = v;
                    const ushort_t* u = (const ushort_t*)&v;
                    float s = bfu2f(u[0])*hA.x + bfu2f(u[1])*hA.y
                            + bfu2f(u[2])*hA.z + bfu2f(u[3])*hA.w
                            + bfu2f(u[4])*hB.x + bfu2f(u[5])*hB.y
                            + bfu2f(u[6])*hB.z + bfu2f(u[7])*hB.w;
                    s += __shfl_xor(s, 1); s += __shfl_xor(s, 2);
                    s += __shfl_xor(s, 4); s += __shfl_xor(s, 8);
                    if (l16 == 0) ew[row] = s;
                }
            }
        } else {
            if (cc == WCHUNK) {
                #pragma unroll
                for (int it = 0; it < WCHUNK / 8; ++it) {
                    const int raw = grp + it * 8, rbw = raw + 4;
                    const float4* xp0 = (const float4*)(x + (size_t)(c0 + raw) * DIM);
                    const float4* xp1 = (const float4*)(x + (size_t)(c0 + rbw) * DIM);
                    float4 xa0 = xp0[l16], xb0 = xp0[l16 + 16];
                    float4 xa1 = xp1[l16], xb1 = xp1[l16 + 16];
                    {
                        float s = xa0.x*h0.x + xa0.y*h0.y + xa0.z*h0.z + xa0.w*h0.w
                                + xb0.x*h1.x + xb0.y*h1.y + xb0.z*h1.z + xb0.w*h1.w;
                        s += __shfl_xor(s, 1); s += __shfl_xor(s, 2);
                        s += __shfl_xor(s, 4); s += __shfl_xor(s, 8);
                        uint2 pa, pb;
                        pa.x = (unsigned)f2bf_u(xa0.x) | ((unsigned)f2bf_u(xa0.y) << 16);
                        pa.y = (unsigned)f2bf_u(xa0.z) | ((unsigned)f2bf_u(xa0.w) << 16);
                        pb.x = (unsigned)f2bf_u(xb0.x) | ((unsigned)f2bf_u(xb0.y) << 16);
                        pb.y = (unsigned)f2bf_u(xb0.z) | ((unsigned)f2bf_u(xb0.w) << 16);
                        *(uint2*)(&xw[raw * 128 + 4 * l16])      = pa;
                        *(uint2*)(&xw[raw * 128 + 64 + 4 * l16]) = pb;
                        if (write_bf) {
                            *(uint2*)(xbf + (size_t)(c0 + raw) * 128 + 4 * l16)      = pa;
                            *(uint2*)(xbf + (size_t)(c0 + raw) * 128 + 64 + 4 * l16) = pb;
                        }
                        if (l16 == 0) ew[raw] = s;
                    }
                    {
                        float s = xa1.x*h0.x + xa1.y*h0.y + xa1.z*h0.z + xa1.w*h0.w
                                + xb1.x*h1.x + xb1.y*h1.y + xb1.z*h1.z + xb1.w*h1.w;
                        s += __shfl_xor(s, 1); s += __shfl_xor(s, 2);
                        s += __shfl_xor(s, 4); s += __shfl_xor(s, 8);
                        uint2 pa, pb;
                        pa.x = (unsigned)f2bf_u(xa1.x) | ((unsigned)f2bf_u(xa1.y) << 16);
                        pa.y = (unsigned)f2bf_u(xa1.z) | ((unsigned)f2bf_u(xa1.w) << 16);
                        pb.x = (unsigned)f2bf_u(xb1.x) | ((unsigned)f2bf_u(xb1.y) << 16);
                        pb.y = (unsigned)f2bf_u(xb1.z) | ((unsigned)f2bf_u(xb1.w) << 16);
                        *(uint2*)(&xw[rbw * 128 + 4 * l16])      = pa;
                        *(uint2*)(&xw[rbw * 128 + 64 + 4 * l16]) = pb;
                        if (write_bf) {
                            *(uint2*)(xbf + (size_t)(c0 + rbw) * 128 + 4 * l16)      = pa;
                            *(uint2*)(xbf + (size_t)(c0 + rbw) * 128 + 64 + 4 * l16) = pb;
                        }
                        if (l16 == 0) ew[rbw] = s;
                    }
                }
            } else {
                for (int j = c0 + grp; j < c0 + cc; j += 4) {
                    const int row = j - c0;
                    const float4* xp = (const float4*)(x + (size_t)j * DIM);
                    float4 xa = xp[l16], xb = xp[l16 + 16];
                    float s = xa.x*h0.x + xa.y*h0.y + xa.z*h0.z + xa.w*h0.w
                            + xb.x*h1.x + xb.y*h1.y + xb.z*h1.z + xb.w*h1.w;
                    s += __shfl_xor(s, 1); s += __shfl_xor(s, 2);
                    s += __shfl_xor(s, 4); s += __shfl_xor(s, 8);
                    uint2 pa, pb;
                    pa.x = (unsigned)f2bf_u(xa.x) | ((unsigned)f2bf_u(xa.y) << 16);
                    pa.y = (unsigned)f2bf_u(xa.z) | ((unsigned)f2bf_u(xa.w) << 16);
                    pb.x = (unsigned)f2bf_u(xb.x) | ((unsigned)f2bf_u(xb.y) << 16);
                    pb.y = (unsigned)f2bf_u(xb.z) | ((unsigned)f2bf_u(xb.w) << 16);
                    *(uint2*)(&xw[row * 128 + 4 * l16])      = pa;
                    *(uint2*)(&xw[row * 128 + 64 + 4 * l16]) = pb;
                    if (write_bf) {
                        *(uint2*)(xbf + (size_t)j * 128 + 4 * l16)      = pa;
                        *(uint2*)(xbf + (size_t)j * 128 + 64 + 4 * l16) = pb;
                    }
                    if (l16 == 0) ew[row] = s;
                }
            }
        }
        LGKM_WAIT();   // es/xs writes visible to whole wave

        // ---- chunk max (64-lane shfl reduce; lanes 32-63 mirror 0-31)
        const int idx = lane & 31;
        float cm = (idx < cc) ? ew[idx] : -INFINITY;
        #pragma unroll
        for (int o = 1; o < 64; o <<= 1) cm = fmaxf(cm, __shfl_xor(cm, o));

        const float mn = fmaxf(m, cm);
        const float scale = expf(m - mn);   // first chunk: exp(-inf)=0

        // ---- exp in place (lanes 0-31) + denom reduce
        float w = 0.f;
        if (lane < 32 && lane < cc) {
            w = expf(ew[lane] - mn);
            ew[lane] = w;
        }
        float cd = w;
        #pragma unroll
        for (int o = 1; o < 64; o <<= 1) cd += __shfl_xor(cd, o);
        LGKM_WAIT();   // exp'd es visible before pass 3 reads

        den = den * scale + cd;
        r0 *= scale;
        r1 *= scale;

        // ---- pass 3: weighted sum from LDS; lane owns dims d0, d0+1
        #pragma unroll 4
        for (int row = 0; row < cc; ++row) {
            float wr = ew[row];   // broadcast read
            unsigned p = *(const unsigned*)(&xw[row * 128 + d0]);
            r0 = fmaf(wr, bfu2f((ushort_t)(p & 0xffff)), r0);
            r1 = fmaf(wr, bfu2f((ushort_t)(p >> 16)), r1);
        }

        m = mn;
    }

    // ---- cross-wave merge (one barrier)
    if (lane == 0) { mstat[wv][0] = m; mstat[wv][1] = den; }
    rbuf[wv][d0]     = r0;
    rbuf[wv][d0 + 1] = r1;
    __syncthreads();

    {
        const float m0s = mstat[0][0], m1s = mstat[1][0];
        const float dn0 = mstat[0][1], dn1 = mstat[1][1];
        const float ms  = fmaxf(m0s, m1s);   // wave0 always has a chunk -> finite
        const float k0  = expf(m0s - ms);
        const float k1  = expf(m1s - ms);    // m1s=-inf (no chunks) -> 0
        const float dtot = k0 * dn0 + k1 * dn1;
        const float rv = (k0 * rbuf[0][tid] + k1 * rbuf[1][tid]) / (dtot + 1e-16f);
        qstar[(size_t)b * 256 + DIM + tid] = rv;
        abuf[(size_t)b * 384 + 128 + tid] = __float2bfloat16(rv);
    }
}

// ---------------------------------------------------------------------------
extern "C" void kernel_launch(void* const* d_in, const int* in_sizes, int n_in,
                              void* d_out, int out_size, void* d_ws, size_t ws_size,
                              hipStream_t stream) {
    const float* x     = (const float*)d_in[0];
    const int*   batch = (const int*)d_in[1];
    const float* Wih   = (const float*)d_in[2];
    const float* Whh   = (const float*)d_in[3];
    const float* bih   = (const float*)d_in[4];
    const float* bhh   = (const float*)d_in[5];
    float* out = (float*)d_out;

    // workspace layout
    float* cbuf  = (float*)d_ws;                            // 8192*128 f32
    float* gates = cbuf + (size_t)NSEG * DIM;               // 8192*512 f32
    __hip_bfloat16* abuf = (__hip_bfloat16*)(gates + (size_t)NSEG * 512);  // 8192*384
    __hip_bfloat16* wbuf = abuf + (size_t)NSEG * 384;       // 512*384
    int* seg = (int*)(wbuf + (size_t)512 * 384);
    // xbf after seg, 16-B aligned
    size_t fixed_bytes = (size_t)((char*)(seg + NSEG + 1) - (char*)d_ws);
    size_t xbf_off = (fixed_bytes + 15) & ~(size_t)15;
    ushort_t* xbf = (ushort_t*)((char*)d_ws + xbf_off);
    size_t need = xbf_off + (size_t)NNODES * DIM * sizeof(ushort_t);
    const int use_xbf = (ws_size >= need) ? 1 : 0;

    seg_bounds_k<<<(NSEG + 256) / 256, 256, 0, stream>>>(batch, seg, NNODES);
    wconv_k<<<(512 * 384) / 256, 256, 0, stream>>>(Wih, Whh, wbuf);

    dim3 ggrid(512 / 64, NSEG / 128);   // (8, 64)
    for (int t = 0; t < TSTEPS; ++t) {
        if (t > 0)
            gemm_mfma_k<<<ggrid, 256, 0, stream>>>(abuf, wbuf, gates);
        const int read_bf  = (use_xbf && t > 0) ? 1 : 0;
        const int write_bf = (use_xbf && t == 0) ? 1 : 0;
        attn_lstm_k<<<NSEG, 128, 0, stream>>>(x, xbf, seg, gates, bih, bhh,
                                              cbuf, out, abuf,
                                              (t == 0) ? 1 : 0, read_bf, write_bf);
    }
}